// Round 1
// baseline (26064.731 us; speedup 1.0000x reference)
//
#include <hip/hip_runtime.h>
#include <math.h>

#define EN 256000
#define NN 40000
#define NR 474
#define EPS_ 1e-5f

__device__ __forceinline__ float bcast(float v, int l) {
    return __uint_as_float(__builtin_amdgcn_readlane(__float_as_uint(v), (unsigned)l));
}
__device__ __forceinline__ float sigm(float x) { return 1.f / (1.f + __expf(-x)); }
__device__ __forceinline__ float tanh_f(float x) { float e = __expf(2.f * x); return 1.f - 2.f / (e + 1.f); }

__device__ __forceinline__ void wave_ln(float v, float& mean, float& var) {
    float s = v, s2 = v * v;
    #pragma unroll
    for (int off = 32; off > 0; off >>= 1) { s += __shfl_xor(s, off, 64); s2 += __shfl_xor(s2, off, 64); }
    mean = s * (1.f / 64.f);
    var = s2 * (1.f / 64.f) - mean * mean;
}

// ---------------- init / graph prep ----------------

__global__ void k_init(float* efeat, float* nfeat, int* cnt, int* outcnt, float* avg_sum) {
    long total = (long)EN * 64;
    for (long i = blockIdx.x * (long)blockDim.x + threadIdx.x; i < total; i += (long)gridDim.x * blockDim.x) {
        efeat[i] = 0.f;
        if (i < (long)NN * 64) nfeat[i] = 0.f;
        if (i < NN) { cnt[i] = 0; outcnt[i] = 0; }
        if (i == 0) avg_sum[0] = 0.f;
    }
}

__global__ void k_count(const int* __restrict__ src, const int* __restrict__ dst, int* cnt, int* outcnt) {
    for (int e = blockIdx.x * blockDim.x + threadIdx.x; e < EN; e += gridDim.x * blockDim.x) {
        atomicAdd(&cnt[dst[e]], 1);
        atomicAdd(&outcnt[src[e]], 1);
    }
}

__global__ void k_scan(const int* __restrict__ cnt, int* __restrict__ row_ptr, int* __restrict__ fillp) {
    __shared__ int sums[1024];
    const int t = threadIdx.x;
    int s = 0;
    for (int i = 0; i < 40; i++) {
        int idx = t * 40 + i;
        if (idx < NN) s += cnt[idx];
    }
    sums[t] = s;
    __syncthreads();
    for (int off = 1; off < 1024; off <<= 1) {
        int v = (t >= off) ? sums[t - off] : 0;
        __syncthreads();
        sums[t] += v;
        __syncthreads();
    }
    int run = (t == 0) ? 0 : sums[t - 1];
    for (int i = 0; i < 40; i++) {
        int idx = t * 40 + i;
        if (idx < NN) { row_ptr[idx] = run; fillp[idx] = run; run += cnt[idx]; }
    }
    if (t == 1023) row_ptr[NN] = run;
}

__global__ void k_fill(const int* __restrict__ dst, int* fillp, int* eid) {
    for (int e = blockIdx.x * blockDim.x + threadIdx.x; e < EN; e += gridDim.x * blockDim.x) {
        int pos = atomicAdd(&fillp[dst[e]], 1);
        eid[pos] = e;
    }
}

__global__ void k_avg(const int* __restrict__ outcnt, float* __restrict__ avg_sum) {
    int n = blockIdx.x * blockDim.x + threadIdx.x;
    float v = 0.f;
    if (n < NN) v = logf((float)outcnt[n] + 1.f);
    #pragma unroll
    for (int off = 32; off > 0; off >>= 1) v += __shfl_xor(v, off, 64);
    if ((threadIdx.x & 63) == 0) atomicAdd(avg_sum, v);
}

__global__ void k_tgt(const int* __restrict__ tgt, const int* __restrict__ etype,
                      const float* __restrict__ query_emb, float* tgt_q, float* efeat) {
    int t = blockIdx.x, d = threadIdx.x;
    int e = tgt[t];
    int r = etype[e];
    float v = query_emb[r * 64 + d];
    tgt_q[t * 64 + d] = v;
    efeat[(size_t)e * 64 + d] = v;
}

__global__ void k_eqg(const float* __restrict__ tgt_q, const float* __restrict__ eqp_w,
                      const float* __restrict__ eqp_b, float* eq_g) {
    int g = blockIdx.x, d = threadIdx.x;
    float acc = eqp_b[d];
    for (int k = 0; k < 128; k++) {
        float a = tgt_q[(2 * g + (k >> 6)) * 64 + (k & 63)];
        acc += a * eqp_w[k * 64 + d];
    }
    eq_g[g * 64 + d] = acc;
}

__global__ void k_equery(const int* __restrict__ egid, const float* __restrict__ eq_g, float* equery) {
    long total = (long)EN * 64;
    for (long i = blockIdx.x * (long)blockDim.x + threadIdx.x; i < total; i += (long)gridDim.x * blockDim.x) {
        int e = (int)(i >> 6), d = (int)(i & 63);
        equery[i] = eq_g[egid[e] * 64 + d];
    }
}

// ---------------- per-layer kernels ----------------

__launch_bounds__(1024)
__global__ void k_gru(const int* __restrict__ src, const int* __restrict__ etype,
                      const float* __restrict__ nfeat, const float* __restrict__ equery,
                      const float* __restrict__ efeat, const float* __restrict__ relw,
                      const float* __restrict__ wx, const float* __restrict__ wh,
                      const float* __restrict__ bx, const float* __restrict__ bh,
                      float* __restrict__ msg) {
    __shared__ float sWx[32 * 192];
    __shared__ float sWh[32 * 192];
    const int tid = threadIdx.x;
    const int lane = tid & 63;
    const int wave = tid >> 6;
    const int e0 = blockIdx.x * 64 + wave * 4;

    float x[4], h[4];
    float ar[4], az[4], an[4], br[4], bz[4], bn[4];
    #pragma unroll
    for (int q = 0; q < 4; q++) {
        int e = e0 + q;
        int s = src[e];
        x[q] = nfeat[s * 64 + lane] + equery[(size_t)e * 64 + lane];
        int ty = etype[e];
        h[q] = efeat[(size_t)e * 64 + lane] * relw[ty * 64 + lane];
        ar[q] = bx[lane];        br[q] = bh[lane];
        az[q] = bx[64 + lane];   bz[q] = bh[64 + lane];
        an[q] = bx[128 + lane];  bn[q] = bh[128 + lane];
    }
    #pragma unroll
    for (int c = 0; c < 2; c++) {
        __syncthreads();
        for (int i = tid; i < 32 * 192; i += 1024) {
            sWx[i] = wx[c * 32 * 192 + i];
            sWh[i] = wh[c * 32 * 192 + i];
        }
        __syncthreads();
        #pragma unroll
        for (int kk = 0; kk < 32; kk++) {
            const int k = c * 32 + kk;
            const float wxr = sWx[kk * 192 + lane];
            const float wxz = sWx[kk * 192 + 64 + lane];
            const float wxn = sWx[kk * 192 + 128 + lane];
            const float whr = sWh[kk * 192 + lane];
            const float whz = sWh[kk * 192 + 64 + lane];
            const float whn = sWh[kk * 192 + 128 + lane];
            #pragma unroll
            for (int q = 0; q < 4; q++) {
                const float xs = bcast(x[q], k);
                const float hs = bcast(h[q], k);
                ar[q] += xs * wxr; az[q] += xs * wxz; an[q] += xs * wxn;
                br[q] += hs * whr; bz[q] += hs * whz; bn[q] += hs * whn;
            }
        }
    }
    #pragma unroll
    for (int q = 0; q < 4; q++) {
        int e = e0 + q;
        float r = sigm(ar[q] + br[q]);
        float z = sigm(az[q] + bz[q]);
        float n = tanh_f(an[q] + r * bn[q]);
        float m = (1.f - z) * n + z * h[q];
        msg[(size_t)e * 64 + lane] = m;
    }
}

__launch_bounds__(1024)
__global__ void k_node(const int* __restrict__ row_ptr, const int* __restrict__ eid,
                       const float* __restrict__ msg, const float* __restrict__ avg_sum,
                       const float* __restrict__ pw, const float* __restrict__ pb,
                       const float* __restrict__ g_ln, const float* __restrict__ b_ln,
                       float* __restrict__ nfeat, float* __restrict__ nfeat_new) {
    __shared__ float sW[3 * 64 * 64];
    const int tid = threadIdx.x, lane = tid & 63, wave = tid >> 6;
    const int v0 = blockIdx.x * 64 + wave * 4;
    const float avg = avg_sum[0] * (1.f / (float)NN);
    float a0[4], a1[4], a2[4], a3[4], samp[4], satt[4];
    #pragma unroll
    for (int q = 0; q < 4; q++) {
        int v = v0 + q;
        int rs = row_ptr[v], re = row_ptr[v + 1];
        float s = 0.f, s2 = 0.f, mx = -INFINITY, mn = INFINITY;
        for (int i = rs; i < re; i++) {
            int e = eid[i];
            float m = msg[(size_t)e * 64 + lane];
            s += m; s2 += m * m; mx = fmaxf(mx, m); mn = fminf(mn, m);
        }
        float deg = (float)(re - rs);
        float dsafe = fmaxf(deg, 1.f);
        float mean = s / dsafe;
        float sq = s2 / dsafe;
        float stdv = sqrtf(fmaxf(sq - mean * mean, 0.f) + EPS_);
        bool has = (re - rs) > 0;
        a0[q] = mean; a1[q] = has ? mx : 0.f; a2[q] = has ? mn : 0.f; a3[q] = stdv;
        float ld = logf(deg + 1.f);
        samp[q] = ld / avg;
        satt[q] = ld > 0.f ? avg / fmaxf(ld, EPS_) : 0.f;
    }
    float y0[4] = {0, 0, 0, 0}, y1[4] = {0, 0, 0, 0}, y2[4] = {0, 0, 0, 0};
    #pragma unroll
    for (int cc = 0; cc < 4; cc++) {
        __syncthreads();
        for (int i = tid; i < 3 * 64 * 64; i += 1024) {
            int sec = i >> 12, r = (i >> 6) & 63, col = i & 63;
            sW[i] = pw[(sec * 256 + cc * 64 + r) * 64 + col];
        }
        __syncthreads();
        #pragma unroll
        for (int kk = 0; kk < 64; kk++) {
            float w0 = sW[kk * 64 + lane];
            float w1 = sW[4096 + kk * 64 + lane];
            float w2 = sW[8192 + kk * 64 + lane];
            #pragma unroll
            for (int q = 0; q < 4; q++) {
                float av;
                if (cc == 0) av = bcast(a0[q], kk);
                else if (cc == 1) av = bcast(a1[q], kk);
                else if (cc == 2) av = bcast(a2[q], kk);
                else av = bcast(a3[q], kk);
                y0[q] += av * w0; y1[q] += av * w1; y2[q] += av * w2;
            }
        }
    }
    #pragma unroll
    for (int q = 0; q < 4; q++) {
        int v = v0 + q;
        float nf = pb[lane] + y0[q] + samp[q] * y1[q] + satt[q] * y2[q];
        nfeat_new[v * 64 + lane] = nf;
        float mean, var;
        wave_ln(nf, mean, var);
        float no = (nf - mean) * rsqrtf(var + EPS_) * g_ln[lane] + b_ln[lane];
        nfeat[v * 64 + lane] += no;
    }
}

__launch_bounds__(1024)
__global__ void k_lstm(const int* __restrict__ dst,
                       const float* __restrict__ nfeat_new,
                       const float* __restrict__ wx, const float* __restrict__ wh,
                       const float* __restrict__ bb,
                       const float* __restrict__ g_ln, const float* __restrict__ b_ln,
                       float* __restrict__ efeat, float* __restrict__ equery) {
    __shared__ float sWx[16 * 256];
    __shared__ float sWh[16 * 256];
    const int tid = threadIdx.x, lane = tid & 63, wave = tid >> 6;
    const int e0 = blockIdx.x * 64 + wave * 4;
    float a[4], ef[4];
    float gi[4], gf[4], gg[4], go[4];
    #pragma unroll
    for (int q = 0; q < 4; q++) {
        int e = e0 + q;
        int v = dst[e];
        a[q] = nfeat_new[v * 64 + lane];
        ef[q] = efeat[(size_t)e * 64 + lane];
        gi[q] = bb[lane]; gf[q] = bb[64 + lane]; gg[q] = bb[128 + lane]; go[q] = bb[192 + lane];
    }
    #pragma unroll
    for (int c = 0; c < 4; c++) {
        __syncthreads();
        for (int i = tid; i < 16 * 256; i += 1024) {
            sWx[i] = wx[c * 16 * 256 + i];
            sWh[i] = wh[c * 16 * 256 + i];
        }
        __syncthreads();
        #pragma unroll
        for (int kk = 0; kk < 16; kk++) {
            const int k = c * 16 + kk;
            float wxi = sWx[kk * 256 + lane], wxf = sWx[kk * 256 + 64 + lane];
            float wxg = sWx[kk * 256 + 128 + lane], wxo = sWx[kk * 256 + 192 + lane];
            float whi = sWh[kk * 256 + lane], whf = sWh[kk * 256 + 64 + lane];
            float whg = sWh[kk * 256 + 128 + lane], who = sWh[kk * 256 + 192 + lane];
            #pragma unroll
            for (int q = 0; q < 4; q++) {
                float as_ = bcast(a[q], k);
                float es_ = bcast(ef[q], k);
                gi[q] += as_ * wxi + es_ * whi;
                gf[q] += as_ * wxf + es_ * whf;
                gg[q] += as_ * wxg + es_ * whg;
                go[q] += as_ * wxo + es_ * who;
            }
        }
    }
    #pragma unroll
    for (int q = 0; q < 4; q++) {
        int e = e0 + q;
        float eq = equery[(size_t)e * 64 + lane];
        float c_ = sigm(gf[q]) * eq + sigm(gi[q]) * tanh_f(gg[q]);
        float hh = sigm(go[q]) * tanh_f(c_);
        float mean, var;
        wave_ln(hh, mean, var);
        float eo = (hh - mean) * rsqrtf(var + EPS_) * g_ln[lane] + b_ln[lane];
        efeat[(size_t)e * 64 + lane] = ef[q] + eo;
        wave_ln(c_, mean, var);
        float qo = (c_ - mean) * rsqrtf(var + EPS_) * g_ln[lane] + b_ln[lane];
        equery[(size_t)e * 64 + lane] = eq + qo;
    }
}

__global__ void k_snap(const int* __restrict__ tgt, const int* __restrict__ src,
                       const float* __restrict__ efeat, const float* __restrict__ equery,
                       const float* __restrict__ nfeat,
                       float* jk_e, float* jk_q, float* jk_n) {
    int t = blockIdx.x, d = threadIdx.x;
    int e = tgt[t];
    jk_e[t * 64 + d] = efeat[(size_t)e * 64 + d];
    jk_q[t * 64 + d] = equery[(size_t)e * 64 + d];
    int v = src[e];
    jk_n[t * 64 + d] = nfeat[v * 64 + d];
}

// ---------------- output head ----------------

__global__ void k_jk(const float* __restrict__ jk_e, const float* __restrict__ jk_q, const float* __restrict__ jk_n,
                     const float* __restrict__ ejk_w, const float* __restrict__ ejk_b,
                     const float* __restrict__ qjk_w, const float* __restrict__ qjk_b,
                     const float* __restrict__ njk_w, const float* __restrict__ njk_b,
                     float* ejk_o, float* qjk_o, float* njk_o) {
    int t = blockIdx.x, d = threadIdx.x;
    float ae = ejk_b[d], aq = qjk_b[d], an_ = njk_b[d];
    for (int l = 0; l < 3; l++) {
        for (int dd = 0; dd < 64; dd++) {
            int k = l * 64 + dd;
            ae += jk_e[(l * 64 + t) * 64 + dd] * ejk_w[k * 64 + d];
            aq += jk_q[(l * 64 + t) * 64 + dd] * qjk_w[k * 64 + d];
            an_ += jk_n[(l * 64 + t) * 64 + dd] * njk_w[k * 64 + d];
        }
    }
    ejk_o[t * 64 + d] = ae;
    qjk_o[t * 64 + d] = aq;
    njk_o[t * 64 + d] = an_;
}

__global__ void k_final(const float* __restrict__ ejk_o, const float* __restrict__ qjk_o,
                        const float* __restrict__ njk_o,
                        const float* __restrict__ fc_w, const float* __restrict__ fc_b,
                        float* out) {
    int b = blockIdx.x, d = threadIdx.x;
    int t0 = 2 * b, t1 = 2 * b + 1;
    float r = ejk_o[t0 * 64 + d] * fc_w[d] + qjk_o[t0 * 64 + d] * fc_w[64 + d]
            + njk_o[t0 * 64 + d] * fc_w[128 + d] + njk_o[t1 * 64 + d] * fc_w[192 + d];
    float lf = ejk_o[t1 * 64 + d] * fc_w[d] + qjk_o[t1 * 64 + d] * fc_w[64 + d]
             + njk_o[t1 * 64 + d] * fc_w[128 + d] + njk_o[t0 * 64 + d] * fc_w[192 + d];
    #pragma unroll
    for (int off = 32; off > 0; off >>= 1) { r += __shfl_xor(r, off, 64); lf += __shfl_xor(lf, off, 64); }
    if (d == 0) out[b] = fmaxf(r + fc_b[0], lf + fc_b[0]);
}

// ---------------- host launcher ----------------

extern "C" void kernel_launch(void* const* d_in, const int* in_sizes, int n_in,
                              void* d_out, int out_size, void* d_ws, size_t ws_size,
                              hipStream_t stream) {
    const int* src   = (const int*)d_in[0];
    const int* dst   = (const int*)d_in[1];
    const int* etype = (const int*)d_in[2];
    const int* egid  = (const int*)d_in[3];
    const int* tgt   = (const int*)d_in[4];
    // d_in[5] = n_nodes (constant 40000)
    const float* query_emb = (const float*)d_in[6];
    const float* eqp_w = (const float*)d_in[7];
    const float* eqp_b = (const float*)d_in[8];
    const float* rel_w = (const float*)d_in[9];
    const float* gru_wx = (const float*)d_in[10];
    const float* gru_wh = (const float*)d_in[11];
    const float* gru_bx = (const float*)d_in[12];
    const float* gru_bh = (const float*)d_in[13];
    const float* pna_w = (const float*)d_in[14];
    const float* pna_b = (const float*)d_in[15];
    const float* lstm_wx = (const float*)d_in[16];
    const float* lstm_wh = (const float*)d_in[17];
    const float* lstm_b = (const float*)d_in[18];
    const float* ln_g = (const float*)d_in[19];
    const float* ln_b = (const float*)d_in[20];
    const float* ejk_w = (const float*)d_in[21];
    const float* ejk_b = (const float*)d_in[22];
    const float* njk_w = (const float*)d_in[23];
    const float* njk_b = (const float*)d_in[24];
    const float* qjk_w = (const float*)d_in[25];
    const float* qjk_b = (const float*)d_in[26];
    const float* fc_w = (const float*)d_in[27];
    const float* fc_b = (const float*)d_in[28];

    float* p = (float*)d_ws;
    float* equery = p;    p += (size_t)EN * 64;
    float* efeat = p;     p += (size_t)EN * 64;
    float* msg = p;       p += (size_t)EN * 64;
    float* nfeat = p;     p += (size_t)NN * 64;
    float* nfeat_new = p; p += (size_t)NN * 64;
    float* tgt_q = p;     p += 64 * 64;
    float* eq_g = p;      p += 32 * 64;
    float* jk_e = p;      p += 3 * 64 * 64;
    float* jk_q = p;      p += 3 * 64 * 64;
    float* jk_n = p;      p += 3 * 64 * 64;
    float* ejk_o = p;     p += 64 * 64;
    float* qjk_o = p;     p += 64 * 64;
    float* njk_o = p;     p += 64 * 64;
    float* avg_sum = p;   p += 64;
    int* ip = (int*)p;
    int* row_ptr = ip; ip += NN + 1;
    int* fillp = ip;   ip += NN;
    int* cnt = ip;     ip += NN;
    int* outcnt = ip;  ip += NN;
    int* eid = ip;     ip += EN;
    if ((size_t)((char*)ip - (char*)d_ws) > ws_size) return;

    k_init<<<4096, 256, 0, stream>>>(efeat, nfeat, cnt, outcnt, avg_sum);
    k_count<<<1024, 256, 0, stream>>>(src, dst, cnt, outcnt);
    k_scan<<<1, 1024, 0, stream>>>(cnt, row_ptr, fillp);
    k_fill<<<1024, 256, 0, stream>>>(dst, fillp, eid);
    k_avg<<<(NN + 255) / 256, 256, 0, stream>>>(outcnt, avg_sum);
    k_tgt<<<64, 64, 0, stream>>>(tgt, etype, query_emb, tgt_q, efeat);
    k_eqg<<<32, 64, 0, stream>>>(tgt_q, eqp_w, eqp_b, eq_g);
    k_equery<<<8192, 256, 0, stream>>>(egid, eq_g, equery);

    for (int l = 0; l < 3; l++) {
        k_gru<<<EN / 64, 1024, 0, stream>>>(src, etype, nfeat, equery, efeat,
            rel_w + (size_t)l * NR * 64,
            gru_wx + (size_t)l * 64 * 192, gru_wh + (size_t)l * 64 * 192,
            gru_bx + (size_t)l * 192, gru_bh + (size_t)l * 192, msg);
        k_node<<<NN / 64, 1024, 0, stream>>>(row_ptr, eid, msg, avg_sum,
            pna_w + (size_t)l * 768 * 64, pna_b + (size_t)l * 64,
            ln_g + (size_t)l * 64, ln_b + (size_t)l * 64, nfeat, nfeat_new);
        k_lstm<<<EN / 64, 1024, 0, stream>>>(dst, nfeat_new,
            lstm_wx + (size_t)l * 64 * 256, lstm_wh + (size_t)l * 64 * 256,
            lstm_b + (size_t)l * 256,
            ln_g + (size_t)l * 64, ln_b + (size_t)l * 64, efeat, equery);
        k_snap<<<64, 64, 0, stream>>>(tgt, src, efeat, equery, nfeat,
            jk_e + l * 4096, jk_q + l * 4096, jk_n + l * 4096);
    }

    k_jk<<<64, 64, 0, stream>>>(jk_e, jk_q, jk_n, ejk_w, ejk_b, qjk_w, qjk_b, njk_w, njk_b,
                                ejk_o, qjk_o, njk_o);
    k_final<<<32, 64, 0, stream>>>(ejk_o, qjk_o, njk_o, fc_w, fc_b, (float*)d_out);
}

// Round 2
// 2424.418 us; speedup vs baseline: 10.7509x; 10.7509x over previous
//
#include <hip/hip_runtime.h>
#include <math.h>

#define EN 256000
#define NN 40000
#define NR 474
#define EPS_ 1e-5f

__device__ __forceinline__ float bcast(float v, int l) {
    return __uint_as_float(__builtin_amdgcn_readlane(__float_as_uint(v), (unsigned)l));
}
__device__ __forceinline__ float sigm(float x) { return 1.f / (1.f + __expf(-x)); }
__device__ __forceinline__ float tanh_f(float x) { float e = __expf(2.f * x); return 1.f - 2.f / (e + 1.f); }

__device__ __forceinline__ void wave_ln(float v, float& mean, float& var) {
    float s = v, s2 = v * v;
    #pragma unroll
    for (int off = 32; off > 0; off >>= 1) { s += __shfl_xor(s, off, 64); s2 += __shfl_xor(s2, off, 64); }
    mean = s * (1.f / 64.f);
    var = s2 * (1.f / 64.f) - mean * mean;
}

// ---------------- init / graph prep ----------------

__global__ void k_init(float* efeat, float* nfeat, int* cnt, int* outcnt, float* avg_sum) {
    long total = (long)EN * 64;
    for (long i = blockIdx.x * (long)blockDim.x + threadIdx.x; i < total; i += (long)gridDim.x * blockDim.x) {
        efeat[i] = 0.f;
        if (i < (long)NN * 64) nfeat[i] = 0.f;
        if (i < NN) { cnt[i] = 0; outcnt[i] = 0; }
        if (i == 0) avg_sum[0] = 0.f;
    }
}

__global__ void k_count(const int* __restrict__ src, const int* __restrict__ dst, int* cnt, int* outcnt) {
    for (int e = blockIdx.x * blockDim.x + threadIdx.x; e < EN; e += gridDim.x * blockDim.x) {
        atomicAdd(&cnt[dst[e]], 1);
        atomicAdd(&outcnt[src[e]], 1);
    }
}

__global__ void k_scan(const int* __restrict__ cnt, int* __restrict__ row_ptr, int* __restrict__ fillp) {
    __shared__ int sums[1024];
    const int t = threadIdx.x;
    int s = 0;
    for (int i = 0; i < 40; i++) {
        int idx = t * 40 + i;
        if (idx < NN) s += cnt[idx];
    }
    sums[t] = s;
    __syncthreads();
    for (int off = 1; off < 1024; off <<= 1) {
        int v = (t >= off) ? sums[t - off] : 0;
        __syncthreads();
        sums[t] += v;
        __syncthreads();
    }
    int run = (t == 0) ? 0 : sums[t - 1];
    for (int i = 0; i < 40; i++) {
        int idx = t * 40 + i;
        if (idx < NN) { row_ptr[idx] = run; fillp[idx] = run; run += cnt[idx]; }
    }
    if (t == 1023) row_ptr[NN] = run;
}

__global__ void k_fill(const int* __restrict__ dst, int* fillp, int* eid) {
    for (int e = blockIdx.x * blockDim.x + threadIdx.x; e < EN; e += gridDim.x * blockDim.x) {
        int pos = atomicAdd(&fillp[dst[e]], 1);
        eid[pos] = e;
    }
}

__global__ void k_avg(const int* __restrict__ outcnt, float* __restrict__ avg_sum) {
    int n = blockIdx.x * blockDim.x + threadIdx.x;
    float v = 0.f;
    if (n < NN) v = logf((float)outcnt[n] + 1.f);
    #pragma unroll
    for (int off = 32; off > 0; off >>= 1) v += __shfl_xor(v, off, 64);
    if ((threadIdx.x & 63) == 0) atomicAdd(avg_sum, v);
}

__global__ void k_tgt(const int* __restrict__ tgt, const int* __restrict__ etype,
                      const float* __restrict__ query_emb, float* tgt_q, float* efeat) {
    int t = blockIdx.x, d = threadIdx.x;
    int e = tgt[t];
    int r = etype[e];
    float v = query_emb[r * 64 + d];
    tgt_q[t * 64 + d] = v;
    efeat[(size_t)e * 64 + d] = v;
}

__global__ void k_eqg(const float* __restrict__ tgt_q, const float* __restrict__ eqp_w,
                      const float* __restrict__ eqp_b, float* eq_g) {
    int g = blockIdx.x, d = threadIdx.x;
    float acc = eqp_b[d];
    for (int k = 0; k < 128; k++) {
        float a = tgt_q[(2 * g + (k >> 6)) * 64 + (k & 63)];
        acc += a * eqp_w[k * 64 + d];
    }
    eq_g[g * 64 + d] = acc;
}

__global__ void k_equery(const int* __restrict__ egid, const float* __restrict__ eq_g, float* equery) {
    long total = (long)EN * 64;
    for (long i = blockIdx.x * (long)blockDim.x + threadIdx.x; i < total; i += (long)gridDim.x * blockDim.x) {
        int e = (int)(i >> 6), d = (int)(i & 63);
        equery[i] = eq_g[egid[e] * 64 + d];
    }
}

// ---------------- per-layer kernels (barrier-free, L2-weight streaming) ----------------

__launch_bounds__(256)
__global__ void k_gru(const int* __restrict__ src, const int* __restrict__ etype,
                      const float* __restrict__ nfeat, const float* __restrict__ equery,
                      const float* __restrict__ efeat, const float* __restrict__ relw,
                      const float* __restrict__ wx, const float* __restrict__ wh,
                      const float* __restrict__ bx, const float* __restrict__ bh,
                      float* __restrict__ msg) {
    const int lane = threadIdx.x & 63;
    const int gw = (blockIdx.x * blockDim.x + threadIdx.x) >> 6;
    const int nw = (gridDim.x * blockDim.x) >> 6;
    const float bxr = bx[lane], bxz = bx[64 + lane], bxn = bx[128 + lane];
    const float bhr = bh[lane], bhz = bh[64 + lane], bhn = bh[128 + lane];
    for (int base = gw * 8; base < EN; base += nw * 8) {
        float x[8], h[8];
        #pragma unroll
        for (int q = 0; q < 8; q++) {
            const int e = base + q;
            const int s = src[e];
            const int ty = etype[e];
            x[q] = nfeat[s * 64 + lane] + equery[(size_t)e * 64 + lane];
            h[q] = efeat[(size_t)e * 64 + lane] * relw[ty * 64 + lane];
        }
        float ar[8], az[8], an[8], br[8], bz[8], bn[8];
        #pragma unroll
        for (int q = 0; q < 8; q++) {
            ar[q] = bxr; az[q] = bxz; an[q] = bxn;
            br[q] = bhr; bz[q] = bhz; bn[q] = bhn;
        }
        #pragma unroll 2
        for (int k = 0; k < 64; k++) {
            const float* wxk = wx + k * 192;
            const float* whk = wh + k * 192;
            const float wxr = wxk[lane], wxz = wxk[64 + lane], wxn = wxk[128 + lane];
            const float whr = whk[lane], whz = whk[64 + lane], whn = whk[128 + lane];
            #pragma unroll
            for (int q = 0; q < 8; q++) {
                const float xs = bcast(x[q], k);
                const float hs = bcast(h[q], k);
                ar[q] += xs * wxr; az[q] += xs * wxz; an[q] += xs * wxn;
                br[q] += hs * whr; bz[q] += hs * whz; bn[q] += hs * whn;
            }
        }
        #pragma unroll
        for (int q = 0; q < 8; q++) {
            const int e = base + q;
            const float r = sigm(ar[q] + br[q]);
            const float z = sigm(az[q] + bz[q]);
            const float n = tanh_f(an[q] + r * bn[q]);
            msg[(size_t)e * 64 + lane] = (1.f - z) * n + z * h[q];
        }
    }
}

__launch_bounds__(256)
__global__ void k_node(const int* __restrict__ row_ptr, const int* __restrict__ eid,
                       const float* __restrict__ msg, const float* __restrict__ avg_sum,
                       const float* __restrict__ pw, const float* __restrict__ pb,
                       const float* __restrict__ g_ln, const float* __restrict__ b_ln,
                       float* __restrict__ nfeat, float* __restrict__ nfeat_new) {
    const int lane = threadIdx.x & 63;
    const int gw = (blockIdx.x * blockDim.x + threadIdx.x) >> 6;
    const int nw = (gridDim.x * blockDim.x) >> 6;
    const float avg = avg_sum[0] * (1.f / (float)NN);
    const float lg = g_ln[lane], lb = b_ln[lane];
    const float pbl = pb[lane];
    for (int base = gw * 4; base < NN; base += nw * 4) {
        float a0[4], a1[4], a2[4], a3[4], samp[4], satt[4];
        #pragma unroll
        for (int q = 0; q < 4; q++) {
            const int v = base + q;
            const int rs = row_ptr[v], re = row_ptr[v + 1];
            float s = 0.f, s2 = 0.f, mx = -INFINITY, mn = INFINITY;
            for (int i = rs; i < re; i++) {
                const int e = eid[i];
                const float m = msg[(size_t)e * 64 + lane];
                s += m; s2 += m * m; mx = fmaxf(mx, m); mn = fminf(mn, m);
            }
            const float deg = (float)(re - rs);
            const float dsafe = fmaxf(deg, 1.f);
            const float mean = s / dsafe;
            const float sq = s2 / dsafe;
            const bool has = (re - rs) > 0;
            a0[q] = mean;
            a1[q] = has ? mx : 0.f;
            a2[q] = has ? mn : 0.f;
            a3[q] = sqrtf(fmaxf(sq - mean * mean, 0.f) + EPS_);
            const float ld = logf(deg + 1.f);
            samp[q] = ld / avg;
            satt[q] = ld > 0.f ? avg / fmaxf(ld, EPS_) : 0.f;
        }
        float y0[4] = {0, 0, 0, 0}, y1[4] = {0, 0, 0, 0}, y2[4] = {0, 0, 0, 0};
        auto do_sec = [&](int s0, const float (&av)[4]) {
            #pragma unroll 2
            for (int dd = 0; dd < 64; dd++) {
                const float* w = pw + (size_t)(s0 * 64 + dd) * 64;
                const float w0 = w[lane];
                const float w1 = w[16384 + lane];
                const float w2 = w[32768 + lane];
                #pragma unroll
                for (int q = 0; q < 4; q++) {
                    const float av_ = bcast(av[q], dd);
                    y0[q] += av_ * w0; y1[q] += av_ * w1; y2[q] += av_ * w2;
                }
            }
        };
        do_sec(0, a0); do_sec(1, a1); do_sec(2, a2); do_sec(3, a3);
        #pragma unroll
        for (int q = 0; q < 4; q++) {
            const int v = base + q;
            const float nf = pbl + y0[q] + samp[q] * y1[q] + satt[q] * y2[q];
            nfeat_new[v * 64 + lane] = nf;
            float mean, var;
            wave_ln(nf, mean, var);
            nfeat[v * 64 + lane] += (nf - mean) * rsqrtf(var + EPS_) * lg + lb;
        }
    }
}

__launch_bounds__(256)
__global__ void k_lstm(const int* __restrict__ dst, const float* __restrict__ nfeat_new,
                       const float* __restrict__ wx, const float* __restrict__ wh,
                       const float* __restrict__ bb,
                       const float* __restrict__ g_ln, const float* __restrict__ b_ln,
                       float* __restrict__ efeat, float* __restrict__ equery) {
    const int lane = threadIdx.x & 63;
    const int gw = (blockIdx.x * blockDim.x + threadIdx.x) >> 6;
    const int nw = (gridDim.x * blockDim.x) >> 6;
    const float bi = bb[lane], bf = bb[64 + lane], bg = bb[128 + lane], bo = bb[192 + lane];
    const float lg = g_ln[lane], lb = b_ln[lane];
    for (int base = gw * 8; base < EN; base += nw * 8) {
        float a[8], ef[8], eq[8];
        #pragma unroll
        for (int q = 0; q < 8; q++) {
            const int e = base + q;
            a[q] = nfeat_new[dst[e] * 64 + lane];
            ef[q] = efeat[(size_t)e * 64 + lane];
            eq[q] = equery[(size_t)e * 64 + lane];
        }
        float gi[8], gf[8], gg[8], go[8];
        #pragma unroll
        for (int q = 0; q < 8; q++) { gi[q] = bi; gf[q] = bf; gg[q] = bg; go[q] = bo; }
        #pragma unroll 2
        for (int k = 0; k < 64; k++) {
            const float* wk = wx + k * 256;
            const float wi = wk[lane], wf = wk[64 + lane], wg = wk[128 + lane], wo = wk[192 + lane];
            #pragma unroll
            for (int q = 0; q < 8; q++) {
                const float s = bcast(a[q], k);
                gi[q] += s * wi; gf[q] += s * wf; gg[q] += s * wg; go[q] += s * wo;
            }
        }
        #pragma unroll 2
        for (int k = 0; k < 64; k++) {
            const float* wk = wh + k * 256;
            const float wi = wk[lane], wf = wk[64 + lane], wg = wk[128 + lane], wo = wk[192 + lane];
            #pragma unroll
            for (int q = 0; q < 8; q++) {
                const float s = bcast(ef[q], k);
                gi[q] += s * wi; gf[q] += s * wf; gg[q] += s * wg; go[q] += s * wo;
            }
        }
        #pragma unroll
        for (int q = 0; q < 8; q++) {
            const int e = base + q;
            const float c_ = sigm(gf[q]) * eq[q] + sigm(gi[q]) * tanh_f(gg[q]);
            const float hh = sigm(go[q]) * tanh_f(c_);
            float mean, var;
            wave_ln(hh, mean, var);
            efeat[(size_t)e * 64 + lane] = ef[q] + (hh - mean) * rsqrtf(var + EPS_) * lg + lb;
            wave_ln(c_, mean, var);
            equery[(size_t)e * 64 + lane] = eq[q] + (c_ - mean) * rsqrtf(var + EPS_) * lg + lb;
        }
    }
}

__global__ void k_snap(const int* __restrict__ tgt, const int* __restrict__ src,
                       const float* __restrict__ efeat, const float* __restrict__ equery,
                       const float* __restrict__ nfeat,
                       float* jk_e, float* jk_q, float* jk_n) {
    int t = blockIdx.x, d = threadIdx.x;
    int e = tgt[t];
    jk_e[t * 64 + d] = efeat[(size_t)e * 64 + d];
    jk_q[t * 64 + d] = equery[(size_t)e * 64 + d];
    int v = src[e];
    jk_n[t * 64 + d] = nfeat[v * 64 + d];
}

// ---------------- output head ----------------

__global__ void k_jk(const float* __restrict__ jk_e, const float* __restrict__ jk_q, const float* __restrict__ jk_n,
                     const float* __restrict__ ejk_w, const float* __restrict__ ejk_b,
                     const float* __restrict__ qjk_w, const float* __restrict__ qjk_b,
                     const float* __restrict__ njk_w, const float* __restrict__ njk_b,
                     float* ejk_o, float* qjk_o, float* njk_o) {
    int t = blockIdx.x, d = threadIdx.x;
    float ae = ejk_b[d], aq = qjk_b[d], an_ = njk_b[d];
    for (int l = 0; l < 3; l++) {
        for (int dd = 0; dd < 64; dd++) {
            int k = l * 64 + dd;
            ae += jk_e[(l * 64 + t) * 64 + dd] * ejk_w[k * 64 + d];
            aq += jk_q[(l * 64 + t) * 64 + dd] * qjk_w[k * 64 + d];
            an_ += jk_n[(l * 64 + t) * 64 + dd] * njk_w[k * 64 + d];
        }
    }
    ejk_o[t * 64 + d] = ae;
    qjk_o[t * 64 + d] = aq;
    njk_o[t * 64 + d] = an_;
}

__global__ void k_final(const float* __restrict__ ejk_o, const float* __restrict__ qjk_o,
                        const float* __restrict__ njk_o,
                        const float* __restrict__ fc_w, const float* __restrict__ fc_b,
                        float* out) {
    int b = blockIdx.x, d = threadIdx.x;
    int t0 = 2 * b, t1 = 2 * b + 1;
    float r = ejk_o[t0 * 64 + d] * fc_w[d] + qjk_o[t0 * 64 + d] * fc_w[64 + d]
            + njk_o[t0 * 64 + d] * fc_w[128 + d] + njk_o[t1 * 64 + d] * fc_w[192 + d];
    float lf = ejk_o[t1 * 64 + d] * fc_w[d] + qjk_o[t1 * 64 + d] * fc_w[64 + d]
             + njk_o[t1 * 64 + d] * fc_w[128 + d] + njk_o[t0 * 64 + d] * fc_w[192 + d];
    #pragma unroll
    for (int off = 32; off > 0; off >>= 1) { r += __shfl_xor(r, off, 64); lf += __shfl_xor(lf, off, 64); }
    if (d == 0) out[b] = fmaxf(r + fc_b[0], lf + fc_b[0]);
}

// ---------------- host launcher ----------------

extern "C" void kernel_launch(void* const* d_in, const int* in_sizes, int n_in,
                              void* d_out, int out_size, void* d_ws, size_t ws_size,
                              hipStream_t stream) {
    const int* src   = (const int*)d_in[0];
    const int* dst   = (const int*)d_in[1];
    const int* etype = (const int*)d_in[2];
    const int* egid  = (const int*)d_in[3];
    const int* tgt   = (const int*)d_in[4];
    const float* query_emb = (const float*)d_in[6];
    const float* eqp_w = (const float*)d_in[7];
    const float* eqp_b = (const float*)d_in[8];
    const float* rel_w = (const float*)d_in[9];
    const float* gru_wx = (const float*)d_in[10];
    const float* gru_wh = (const float*)d_in[11];
    const float* gru_bx = (const float*)d_in[12];
    const float* gru_bh = (const float*)d_in[13];
    const float* pna_w = (const float*)d_in[14];
    const float* pna_b = (const float*)d_in[15];
    const float* lstm_wx = (const float*)d_in[16];
    const float* lstm_wh = (const float*)d_in[17];
    const float* lstm_b = (const float*)d_in[18];
    const float* ln_g = (const float*)d_in[19];
    const float* ln_b = (const float*)d_in[20];
    const float* ejk_w = (const float*)d_in[21];
    const float* ejk_b = (const float*)d_in[22];
    const float* njk_w = (const float*)d_in[23];
    const float* njk_b = (const float*)d_in[24];
    const float* qjk_w = (const float*)d_in[25];
    const float* qjk_b = (const float*)d_in[26];
    const float* fc_w = (const float*)d_in[27];
    const float* fc_b = (const float*)d_in[28];

    float* p = (float*)d_ws;
    float* equery = p;    p += (size_t)EN * 64;
    float* efeat = p;     p += (size_t)EN * 64;
    float* msg = p;       p += (size_t)EN * 64;
    float* nfeat = p;     p += (size_t)NN * 64;
    float* nfeat_new = p; p += (size_t)NN * 64;
    float* tgt_q = p;     p += 64 * 64;
    float* eq_g = p;      p += 32 * 64;
    float* jk_e = p;      p += 3 * 64 * 64;
    float* jk_q = p;      p += 3 * 64 * 64;
    float* jk_n = p;      p += 3 * 64 * 64;
    float* ejk_o = p;     p += 64 * 64;
    float* qjk_o = p;     p += 64 * 64;
    float* njk_o = p;     p += 64 * 64;
    float* avg_sum = p;   p += 64;
    int* ip = (int*)p;
    int* row_ptr = ip; ip += NN + 1;
    int* fillp = ip;   ip += NN;
    int* cnt = ip;     ip += NN;
    int* outcnt = ip;  ip += NN;
    int* eid = ip;     ip += EN;
    if ((size_t)((char*)ip - (char*)d_ws) > ws_size) return;

    k_init<<<4096, 256, 0, stream>>>(efeat, nfeat, cnt, outcnt, avg_sum);
    k_count<<<1024, 256, 0, stream>>>(src, dst, cnt, outcnt);
    k_scan<<<1, 1024, 0, stream>>>(cnt, row_ptr, fillp);
    k_fill<<<1024, 256, 0, stream>>>(dst, fillp, eid);
    k_avg<<<(NN + 255) / 256, 256, 0, stream>>>(outcnt, avg_sum);
    k_tgt<<<64, 64, 0, stream>>>(tgt, etype, query_emb, tgt_q, efeat);
    k_eqg<<<32, 64, 0, stream>>>(tgt_q, eqp_w, eqp_b, eq_g);
    k_equery<<<8192, 256, 0, stream>>>(egid, eq_g, equery);

    for (int l = 0; l < 3; l++) {
        k_gru<<<2000, 256, 0, stream>>>(src, etype, nfeat, equery, efeat,
            rel_w + (size_t)l * NR * 64,
            gru_wx + (size_t)l * 64 * 192, gru_wh + (size_t)l * 64 * 192,
            gru_bx + (size_t)l * 192, gru_bh + (size_t)l * 192, msg);
        k_node<<<2500, 256, 0, stream>>>(row_ptr, eid, msg, avg_sum,
            pna_w + (size_t)l * 768 * 64, pna_b + (size_t)l * 64,
            ln_g + (size_t)l * 64, ln_b + (size_t)l * 64, nfeat, nfeat_new);
        k_lstm<<<2000, 256, 0, stream>>>(dst, nfeat_new,
            lstm_wx + (size_t)l * 64 * 256, lstm_wh + (size_t)l * 64 * 256,
            lstm_b + (size_t)l * 256,
            ln_g + (size_t)l * 64, ln_b + (size_t)l * 64, efeat, equery);
        k_snap<<<64, 64, 0, stream>>>(tgt, src, efeat, equery, nfeat,
            jk_e + l * 4096, jk_q + l * 4096, jk_n + l * 4096);
    }

    k_jk<<<64, 64, 0, stream>>>(jk_e, jk_q, jk_n, ejk_w, ejk_b, qjk_w, qjk_b, njk_w, njk_b,
                                ejk_o, qjk_o, njk_o);
    k_final<<<32, 64, 0, stream>>>(ejk_o, qjk_o, njk_o, fc_w, fc_b, (float*)d_out);
}

// Round 3
// 1479.987 us; speedup vs baseline: 17.6115x; 1.6381x over previous
//
#include <hip/hip_runtime.h>
#include <math.h>

#define EN 256000
#define NN 40000
#define NR 474
#define EPS_ 1e-5f

typedef __attribute__((ext_vector_type(4))) float f4_t;
typedef __attribute__((ext_vector_type(8))) short bf8_t;
typedef __attribute__((ext_vector_type(4))) float facc_t;

__device__ __forceinline__ float sigm(float x) { return 1.f / (1.f + __expf(-x)); }
__device__ __forceinline__ float tanh_f(float x) { float e = __expf(2.f * x); return 1.f - 2.f / (e + 1.f); }

__device__ __forceinline__ short f2bf(float f) {
    unsigned u = __float_as_uint(f);
    return (short)((u + 0x7FFFu + ((u >> 16) & 1u)) >> 16);
}
__device__ __forceinline__ bf8_t pack8(f4_t a, f4_t b) {
    bf8_t r;
    r[0] = f2bf(a[0]); r[1] = f2bf(a[1]); r[2] = f2bf(a[2]); r[3] = f2bf(a[3]);
    r[4] = f2bf(b[0]); r[5] = f2bf(b[1]); r[6] = f2bf(b[2]); r[7] = f2bf(b[3]);
    return r;
}

__device__ __forceinline__ void wave_ln(float v, float& mean, float& var) {
    float s = v, s2 = v * v;
    #pragma unroll
    for (int off = 32; off > 0; off >>= 1) { s += __shfl_xor(s, off, 64); s2 += __shfl_xor(s2, off, 64); }
    mean = s * (1.f / 64.f);
    var = s2 * (1.f / 64.f) - mean * mean;
}

// ---------------- init / graph prep ----------------

__global__ void k_init(float* efeat, float* nfeat, int* cnt, int* outcnt, float* avg_sum) {
    long total = (long)EN * 64;
    for (long i = blockIdx.x * (long)blockDim.x + threadIdx.x; i < total; i += (long)gridDim.x * blockDim.x) {
        efeat[i] = 0.f;
        if (i < (long)NN * 64) nfeat[i] = 0.f;
        if (i < NN) { cnt[i] = 0; outcnt[i] = 0; }
        if (i == 0) avg_sum[0] = 0.f;
    }
}

__global__ void k_count(const int* __restrict__ src, const int* __restrict__ dst, int* cnt, int* outcnt) {
    for (int e = blockIdx.x * blockDim.x + threadIdx.x; e < EN; e += gridDim.x * blockDim.x) {
        atomicAdd(&cnt[dst[e]], 1);
        atomicAdd(&outcnt[src[e]], 1);
    }
}

__global__ void k_scan(const int* __restrict__ cnt, int* __restrict__ row_ptr, int* __restrict__ fillp) {
    __shared__ int sums[1024];
    const int t = threadIdx.x;
    int s = 0;
    for (int i = 0; i < 40; i++) {
        int idx = t * 40 + i;
        if (idx < NN) s += cnt[idx];
    }
    sums[t] = s;
    __syncthreads();
    for (int off = 1; off < 1024; off <<= 1) {
        int v = (t >= off) ? sums[t - off] : 0;
        __syncthreads();
        sums[t] += v;
        __syncthreads();
    }
    int run = (t == 0) ? 0 : sums[t - 1];
    for (int i = 0; i < 40; i++) {
        int idx = t * 40 + i;
        if (idx < NN) { row_ptr[idx] = run; fillp[idx] = run; run += cnt[idx]; }
    }
    if (t == 1023) row_ptr[NN] = run;
}

__global__ void k_fill(const int* __restrict__ dst, int* fillp, int* eid) {
    for (int e = blockIdx.x * blockDim.x + threadIdx.x; e < EN; e += gridDim.x * blockDim.x) {
        int pos = atomicAdd(&fillp[dst[e]], 1);
        eid[pos] = e;
    }
}

__global__ void k_avg(const int* __restrict__ outcnt, float* __restrict__ avg_sum) {
    int n = blockIdx.x * blockDim.x + threadIdx.x;
    float v = 0.f;
    if (n < NN) v = logf((float)outcnt[n] + 1.f);
    #pragma unroll
    for (int off = 32; off > 0; off >>= 1) v += __shfl_xor(v, off, 64);
    if ((threadIdx.x & 63) == 0) atomicAdd(avg_sum, v);
}

__global__ void k_tgt(const int* __restrict__ tgt, const int* __restrict__ etype,
                      const float* __restrict__ query_emb, float* tgt_q, float* efeat) {
    int t = blockIdx.x, d = threadIdx.x;
    int e = tgt[t];
    int r = etype[e];
    float v = query_emb[r * 64 + d];
    tgt_q[t * 64 + d] = v;
    efeat[(size_t)e * 64 + d] = v;
}

__global__ void k_eqg(const float* __restrict__ tgt_q, const float* __restrict__ eqp_w,
                      const float* __restrict__ eqp_b, float* eq_g) {
    int g = blockIdx.x, d = threadIdx.x;
    float acc = eqp_b[d];
    for (int k = 0; k < 128; k++) {
        float a = tgt_q[(2 * g + (k >> 6)) * 64 + (k & 63)];
        acc += a * eqp_w[k * 64 + d];
    }
    eq_g[g * 64 + d] = acc;
}

__global__ void k_equery(const int* __restrict__ egid, const float* __restrict__ eq_g, float* equery) {
    long total = (long)EN * 64;
    for (long i = blockIdx.x * (long)blockDim.x + threadIdx.x; i < total; i += (long)gridDim.x * blockDim.x) {
        int e = (int)(i >> 6), d = (int)(i & 63);
        equery[i] = eq_g[egid[e] * 64 + d];
    }
}

// ---------------- weight packing for MFMA ----------------
// Record layout: rec = (ks*16 + nt)*64 + lane; elem j=0..7:
//   W[k][c] with k = ks*32 + (lane>>4)*8 + j,  c = 16*nt + (lane&15)
// Column meaning: nt = w*4 + g; d = 16*w + (lane&15).

__global__ void k_pack_gru(const float* __restrict__ wx, const float* __restrict__ wh,
                           unsigned short* __restrict__ out) {
    int l = blockIdx.y;
    wx += (size_t)l * 64 * 192; wh += (size_t)l * 64 * 192; out += (size_t)l * 32768;
    for (int idx = blockIdx.x * blockDim.x + threadIdx.x; idx < 32768; idx += gridDim.x * blockDim.x) {
        int rec = idx >> 3, j = idx & 7;
        int lane = rec & 63, ksnt = rec >> 6;
        int nt = ksnt & 15, ks = ksnt >> 4;
        int k = ks * 32 + (lane >> 4) * 8 + j;
        int g = nt & 3, d = (nt >> 2) * 16 + (lane & 15);
        float v;
        if (g == 0)      v = k < 64 ? wx[k * 192 + d]        : wh[(k - 64) * 192 + d];
        else if (g == 1) v = k < 64 ? wx[k * 192 + 64 + d]   : wh[(k - 64) * 192 + 64 + d];
        else if (g == 2) v = k < 64 ? wx[k * 192 + 128 + d]  : 0.f;
        else             v = k < 64 ? 0.f                    : wh[(k - 64) * 192 + 128 + d];
        out[idx] = (unsigned short)f2bf(v);
    }
}

__global__ void k_pack_lstm(const float* __restrict__ wx, const float* __restrict__ wh,
                            unsigned short* __restrict__ out) {
    int l = blockIdx.y;
    wx += (size_t)l * 64 * 256; wh += (size_t)l * 64 * 256; out += (size_t)l * 32768;
    for (int idx = blockIdx.x * blockDim.x + threadIdx.x; idx < 32768; idx += gridDim.x * blockDim.x) {
        int rec = idx >> 3, j = idx & 7;
        int lane = rec & 63, ksnt = rec >> 6;
        int nt = ksnt & 15, ks = ksnt >> 4;
        int k = ks * 32 + (lane >> 4) * 8 + j;
        int g = nt & 3, d = (nt >> 2) * 16 + (lane & 15);
        float v = k < 64 ? wx[k * 256 + g * 64 + d] : wh[(k - 64) * 256 + g * 64 + d];
        out[idx] = (unsigned short)f2bf(v);
    }
}

// ---------------- per-layer kernels ----------------

__launch_bounds__(256)
__global__ void k_gru(const int* __restrict__ src, const int* __restrict__ etype,
                      const float* __restrict__ nfeat, const float* __restrict__ equery,
                      const float* __restrict__ efeat, const float* __restrict__ relw,
                      const unsigned short* __restrict__ wpack,
                      const float* __restrict__ bx, const float* __restrict__ bh,
                      float* __restrict__ msg) {
    const int lane = threadIdx.x & 63;
    const int w = threadIdx.x >> 6;
    const int row = lane & 15, kg = lane >> 4, dd = lane & 15;
    const int d = w * 16 + dd;
    bf8_t bf[4][4];
    #pragma unroll
    for (int ks = 0; ks < 4; ks++) {
        #pragma unroll
        for (int g = 0; g < 4; g++)
            bf[ks][g] = ((const bf8_t*)wpack)[(ks * 16 + w * 4 + g) * 64 + lane];
    }
    const float br_ = bx[d] + bh[d];
    const float bz_ = bx[64 + d] + bh[64 + d];
    const float bxn = bx[128 + d], bhn = bh[128 + d];
    for (int base = blockIdx.x * 16; base < EN; base += gridDim.x * 16) {
        const int e = base + row;
        const int s = src[e], ty = etype[e];
        bf8_t af[4];
        #pragma unroll
        for (int ks = 0; ks < 2; ks++) {
            const int kb = ks * 32 + kg * 8;
            f4_t n0 = *(const f4_t*)(nfeat + s * 64 + kb);
            f4_t n1 = *(const f4_t*)(nfeat + s * 64 + kb + 4);
            f4_t q0 = *(const f4_t*)(equery + (size_t)e * 64 + kb);
            f4_t q1 = *(const f4_t*)(equery + (size_t)e * 64 + kb + 4);
            af[ks] = pack8(n0 + q0, n1 + q1);
        }
        #pragma unroll
        for (int ks = 2; ks < 4; ks++) {
            const int kb = (ks - 2) * 32 + kg * 8;
            f4_t e0 = *(const f4_t*)(efeat + (size_t)e * 64 + kb);
            f4_t e1 = *(const f4_t*)(efeat + (size_t)e * 64 + kb + 4);
            f4_t r0 = *(const f4_t*)(relw + ty * 64 + kb);
            f4_t r1 = *(const f4_t*)(relw + ty * 64 + kb + 4);
            af[ks] = pack8(e0 * r0, e1 * r1);
        }
        facc_t ar = {0.f, 0.f, 0.f, 0.f}, az = ar, axn = ar, ahn = ar;
        #pragma unroll
        for (int ks = 0; ks < 4; ks++) {
            ar  = __builtin_amdgcn_mfma_f32_16x16x32_bf16(af[ks], bf[ks][0], ar, 0, 0, 0);
            az  = __builtin_amdgcn_mfma_f32_16x16x32_bf16(af[ks], bf[ks][1], az, 0, 0, 0);
            axn = __builtin_amdgcn_mfma_f32_16x16x32_bf16(af[ks], bf[ks][2], axn, 0, 0, 0);
            ahn = __builtin_amdgcn_mfma_f32_16x16x32_bf16(af[ks], bf[ks][3], ahn, 0, 0, 0);
        }
        #pragma unroll
        for (int rr = 0; rr < 4; rr++) {
            const int er = base + kg * 4 + rr;
            const float r_ = sigm(ar[rr] + br_);
            const float z_ = sigm(az[rr] + bz_);
            const float n_ = tanh_f(axn[rr] + bxn + r_ * (ahn[rr] + bhn));
            const int tyr = etype[er];
            const float h_ = efeat[(size_t)er * 64 + d] * relw[tyr * 64 + d];
            msg[(size_t)er * 64 + d] = (1.f - z_) * n_ + z_ * h_;
        }
    }
}

__launch_bounds__(256)
__global__ void k_lstm(const int* __restrict__ dst, const float* __restrict__ nfeat_new,
                       const unsigned short* __restrict__ wpack, const float* __restrict__ bb,
                       const float* __restrict__ g_ln, const float* __restrict__ b_ln,
                       float* __restrict__ efeat, float* __restrict__ equery) {
    __shared__ float red[4][16][4];
    const int lane = threadIdx.x & 63;
    const int w = threadIdx.x >> 6;
    const int row = lane & 15, kg = lane >> 4, dd = lane & 15;
    const int d = w * 16 + dd;
    bf8_t bf[4][4];
    #pragma unroll
    for (int ks = 0; ks < 4; ks++) {
        #pragma unroll
        for (int g = 0; g < 4; g++)
            bf[ks][g] = ((const bf8_t*)wpack)[(ks * 16 + w * 4 + g) * 64 + lane];
    }
    const float bi = bb[d], bfb = bb[64 + d], bg = bb[128 + d], bo = bb[192 + d];
    const float lg = g_ln[d], lb = b_ln[d];
    for (int base = blockIdx.x * 16; base < EN; base += gridDim.x * 16) {
        const int e = base + row;
        const int de = dst[e];
        bf8_t af[4];
        #pragma unroll
        for (int ks = 0; ks < 2; ks++) {
            const int kb = ks * 32 + kg * 8;
            f4_t v0 = *(const f4_t*)(nfeat_new + de * 64 + kb);
            f4_t v1 = *(const f4_t*)(nfeat_new + de * 64 + kb + 4);
            af[ks] = pack8(v0, v1);
        }
        #pragma unroll
        for (int ks = 2; ks < 4; ks++) {
            const int kb = (ks - 2) * 32 + kg * 8;
            f4_t v0 = *(const f4_t*)(efeat + (size_t)e * 64 + kb);
            f4_t v1 = *(const f4_t*)(efeat + (size_t)e * 64 + kb + 4);
            af[ks] = pack8(v0, v1);
        }
        facc_t ai = {0.f, 0.f, 0.f, 0.f}, af_ = ai, ag = ai, ao = ai;
        #pragma unroll
        for (int ks = 0; ks < 4; ks++) {
            ai  = __builtin_amdgcn_mfma_f32_16x16x32_bf16(af[ks], bf[ks][0], ai, 0, 0, 0);
            af_ = __builtin_amdgcn_mfma_f32_16x16x32_bf16(af[ks], bf[ks][1], af_, 0, 0, 0);
            ag  = __builtin_amdgcn_mfma_f32_16x16x32_bf16(af[ks], bf[ks][2], ag, 0, 0, 0);
            ao  = __builtin_amdgcn_mfma_f32_16x16x32_bf16(af[ks], bf[ks][3], ao, 0, 0, 0);
        }
        float hh[4], cc[4], eqs[4];
        #pragma unroll
        for (int rr = 0; rr < 4; rr++) {
            const int er = base + kg * 4 + rr;
            eqs[rr] = equery[(size_t)er * 64 + d];
            const float ci = sigm(ai[rr] + bi);
            const float cf = sigm(af_[rr] + bfb);
            const float cg = tanh_f(ag[rr] + bg);
            const float co = sigm(ao[rr] + bo);
            const float c_ = cf * eqs[rr] + ci * cg;
            cc[rr] = c_;
            hh[rr] = co * tanh_f(c_);
        }
        float hs[4], hs2[4], cs[4], cs2[4];
        #pragma unroll
        for (int rr = 0; rr < 4; rr++) { hs[rr] = hh[rr]; hs2[rr] = hh[rr] * hh[rr]; cs[rr] = cc[rr]; cs2[rr] = cc[rr] * cc[rr]; }
        #pragma unroll
        for (int off = 1; off < 16; off <<= 1) {
            #pragma unroll
            for (int rr = 0; rr < 4; rr++) {
                hs[rr] += __shfl_xor(hs[rr], off, 64);
                hs2[rr] += __shfl_xor(hs2[rr], off, 64);
                cs[rr] += __shfl_xor(cs[rr], off, 64);
                cs2[rr] += __shfl_xor(cs2[rr], off, 64);
            }
        }
        __syncthreads();
        if (dd == 0) {
            #pragma unroll
            for (int rr = 0; rr < 4; rr++) {
                red[w][kg * 4 + rr][0] = hs[rr];
                red[w][kg * 4 + rr][1] = hs2[rr];
                red[w][kg * 4 + rr][2] = cs[rr];
                red[w][kg * 4 + rr][3] = cs2[rr];
            }
        }
        __syncthreads();
        #pragma unroll
        for (int rr = 0; rr < 4; rr++) {
            const int el = kg * 4 + rr;
            float th = 0.f, th2 = 0.f, tc = 0.f, tc2 = 0.f;
            #pragma unroll
            for (int w2 = 0; w2 < 4; w2++) {
                th += red[w2][el][0]; th2 += red[w2][el][1];
                tc += red[w2][el][2]; tc2 += red[w2][el][3];
            }
            const float hm = th * (1.f / 64.f), hv = th2 * (1.f / 64.f) - hm * hm;
            const float cm = tc * (1.f / 64.f), cv = tc2 * (1.f / 64.f) - cm * cm;
            const int er = base + kg * 4 + rr;
            const size_t off = (size_t)er * 64 + d;
            efeat[off] = efeat[off] + (hh[rr] - hm) * rsqrtf(hv + EPS_) * lg + lb;
            equery[off] = eqs[rr] + (cc[rr] - cm) * rsqrtf(cv + EPS_) * lg + lb;
        }
    }
}

__launch_bounds__(256)
__global__ void k_node(const int* __restrict__ row_ptr, const int* __restrict__ eid,
                       const float* __restrict__ msg, const float* __restrict__ avg_sum,
                       const float* __restrict__ pw, const float* __restrict__ pb,
                       const float* __restrict__ g_ln, const float* __restrict__ b_ln,
                       float* __restrict__ nfeat, float* __restrict__ nfeat_new) {
    const int lane = threadIdx.x & 63;
    const int gw = (blockIdx.x * blockDim.x + threadIdx.x) >> 6;
    const int nw = (gridDim.x * blockDim.x) >> 6;
    const float avg = avg_sum[0] * (1.f / (float)NN);
    const float lg = g_ln[lane], lb = b_ln[lane];
    const float pbl = pb[lane];
    for (int base = gw * 4; base < NN; base += nw * 4) {
        float a0[4], a1[4], a2[4], a3[4], samp[4], satt[4];
        #pragma unroll
        for (int q = 0; q < 4; q++) {
            const int v = base + q;
            const int rs = row_ptr[v], re = row_ptr[v + 1];
            float s = 0.f, s2 = 0.f, mx = -INFINITY, mn = INFINITY;
            for (int i = rs; i < re; i++) {
                const int e = eid[i];
                const float m = msg[(size_t)e * 64 + lane];
                s += m; s2 += m * m; mx = fmaxf(mx, m); mn = fminf(mn, m);
            }
            const float deg = (float)(re - rs);
            const float dsafe = fmaxf(deg, 1.f);
            const float mean = s / dsafe;
            const float sq = s2 / dsafe;
            const bool has = (re - rs) > 0;
            a0[q] = mean;
            a1[q] = has ? mx : 0.f;
            a2[q] = has ? mn : 0.f;
            a3[q] = sqrtf(fmaxf(sq - mean * mean, 0.f) + EPS_);
            const float ld = logf(deg + 1.f);
            samp[q] = ld / avg;
            satt[q] = ld > 0.f ? avg / fmaxf(ld, EPS_) : 0.f;
        }
        float y0[4] = {0, 0, 0, 0}, y1[4] = {0, 0, 0, 0}, y2[4] = {0, 0, 0, 0};
        auto do_sec = [&](int s0, const float (&av)[4]) {
            #pragma unroll 2
            for (int dd = 0; dd < 64; dd++) {
                const float* w = pw + (size_t)(s0 * 64 + dd) * 64;
                const float w0 = w[lane];
                const float w1 = w[16384 + lane];
                const float w2 = w[32768 + lane];
                #pragma unroll
                for (int q = 0; q < 4; q++) {
                    const float av_ = __uint_as_float(__builtin_amdgcn_readlane(__float_as_uint(av[q]), (unsigned)dd));
                    y0[q] += av_ * w0; y1[q] += av_ * w1; y2[q] += av_ * w2;
                }
            }
        };
        do_sec(0, a0); do_sec(1, a1); do_sec(2, a2); do_sec(3, a3);
        #pragma unroll
        for (int q = 0; q < 4; q++) {
            const int v = base + q;
            const float nf = pbl + y0[q] + samp[q] * y1[q] + satt[q] * y2[q];
            nfeat_new[v * 64 + lane] = nf;
            float mean, var;
            wave_ln(nf, mean, var);
            nfeat[v * 64 + lane] += (nf - mean) * rsqrtf(var + EPS_) * lg + lb;
        }
    }
}

__global__ void k_snap(const int* __restrict__ tgt, const int* __restrict__ src,
                       const float* __restrict__ efeat, const float* __restrict__ equery,
                       const float* __restrict__ nfeat,
                       float* jk_e, float* jk_q, float* jk_n) {
    int t = blockIdx.x, d = threadIdx.x;
    int e = tgt[t];
    jk_e[t * 64 + d] = efeat[(size_t)e * 64 + d];
    jk_q[t * 64 + d] = equery[(size_t)e * 64 + d];
    int v = src[e];
    jk_n[t * 64 + d] = nfeat[v * 64 + d];
}

// ---------------- output head ----------------

__global__ void k_jk(const float* __restrict__ jk_e, const float* __restrict__ jk_q, const float* __restrict__ jk_n,
                     const float* __restrict__ ejk_w, const float* __restrict__ ejk_b,
                     const float* __restrict__ qjk_w, const float* __restrict__ qjk_b,
                     const float* __restrict__ njk_w, const float* __restrict__ njk_b,
                     float* ejk_o, float* qjk_o, float* njk_o) {
    int t = blockIdx.x, d = threadIdx.x;
    float ae = ejk_b[d], aq = qjk_b[d], an_ = njk_b[d];
    for (int l = 0; l < 3; l++) {
        for (int dd = 0; dd < 64; dd++) {
            int k = l * 64 + dd;
            ae += jk_e[(l * 64 + t) * 64 + dd] * ejk_w[k * 64 + d];
            aq += jk_q[(l * 64 + t) * 64 + dd] * qjk_w[k * 64 + d];
            an_ += jk_n[(l * 64 + t) * 64 + dd] * njk_w[k * 64 + d];
        }
    }
    ejk_o[t * 64 + d] = ae;
    qjk_o[t * 64 + d] = aq;
    njk_o[t * 64 + d] = an_;
}

__global__ void k_final(const float* __restrict__ ejk_o, const float* __restrict__ qjk_o,
                        const float* __restrict__ njk_o,
                        const float* __restrict__ fc_w, const float* __restrict__ fc_b,
                        float* out) {
    int b = blockIdx.x, d = threadIdx.x;
    int t0 = 2 * b, t1 = 2 * b + 1;
    float r = ejk_o[t0 * 64 + d] * fc_w[d] + qjk_o[t0 * 64 + d] * fc_w[64 + d]
            + njk_o[t0 * 64 + d] * fc_w[128 + d] + njk_o[t1 * 64 + d] * fc_w[192 + d];
    float lf = ejk_o[t1 * 64 + d] * fc_w[d] + qjk_o[t1 * 64 + d] * fc_w[64 + d]
             + njk_o[t1 * 64 + d] * fc_w[128 + d] + njk_o[t0 * 64 + d] * fc_w[192 + d];
    #pragma unroll
    for (int off = 32; off > 0; off >>= 1) { r += __shfl_xor(r, off, 64); lf += __shfl_xor(lf, off, 64); }
    if (d == 0) out[b] = fmaxf(r + fc_b[0], lf + fc_b[0]);
}

// ---------------- host launcher ----------------

extern "C" void kernel_launch(void* const* d_in, const int* in_sizes, int n_in,
                              void* d_out, int out_size, void* d_ws, size_t ws_size,
                              hipStream_t stream) {
    const int* src   = (const int*)d_in[0];
    const int* dst   = (const int*)d_in[1];
    const int* etype = (const int*)d_in[2];
    const int* egid  = (const int*)d_in[3];
    const int* tgt   = (const int*)d_in[4];
    const float* query_emb = (const float*)d_in[6];
    const float* eqp_w = (const float*)d_in[7];
    const float* eqp_b = (const float*)d_in[8];
    const float* rel_w = (const float*)d_in[9];
    const float* gru_wx = (const float*)d_in[10];
    const float* gru_wh = (const float*)d_in[11];
    const float* gru_bx = (const float*)d_in[12];
    const float* gru_bh = (const float*)d_in[13];
    const float* pna_w = (const float*)d_in[14];
    const float* pna_b = (const float*)d_in[15];
    const float* lstm_wx = (const float*)d_in[16];
    const float* lstm_wh = (const float*)d_in[17];
    const float* lstm_b = (const float*)d_in[18];
    const float* ln_g = (const float*)d_in[19];
    const float* ln_b = (const float*)d_in[20];
    const float* ejk_w = (const float*)d_in[21];
    const float* ejk_b = (const float*)d_in[22];
    const float* njk_w = (const float*)d_in[23];
    const float* njk_b = (const float*)d_in[24];
    const float* qjk_w = (const float*)d_in[25];
    const float* qjk_b = (const float*)d_in[26];
    const float* fc_w = (const float*)d_in[27];
    const float* fc_b = (const float*)d_in[28];

    float* p = (float*)d_ws;
    float* equery = p;    p += (size_t)EN * 64;
    float* efeat = p;     p += (size_t)EN * 64;
    float* msg = p;       p += (size_t)EN * 64;
    float* nfeat = p;     p += (size_t)NN * 64;
    float* nfeat_new = p; p += (size_t)NN * 64;
    float* tgt_q = p;     p += 64 * 64;
    float* eq_g = p;      p += 32 * 64;
    float* jk_e = p;      p += 3 * 64 * 64;
    float* jk_q = p;      p += 3 * 64 * 64;
    float* jk_n = p;      p += 3 * 64 * 64;
    float* ejk_o = p;     p += 64 * 64;
    float* qjk_o = p;     p += 64 * 64;
    float* njk_o = p;     p += 64 * 64;
    float* avg_sum = p;   p += 64;
    unsigned short* wpg = (unsigned short*)p;   // 3*32768 bf16
    unsigned short* wpl = wpg + 3 * 32768;      // 3*32768 bf16
    int* ip = (int*)(wpl + 3 * 32768);
    int* row_ptr = ip; ip += NN + 1;
    int* fillp = ip;   ip += NN;
    int* cnt = ip;     ip += NN;
    int* outcnt = ip;  ip += NN;
    int* eid = ip;     ip += EN;
    if ((size_t)((char*)ip - (char*)d_ws) > ws_size) return;

    k_init<<<4096, 256, 0, stream>>>(efeat, nfeat, cnt, outcnt, avg_sum);
    k_count<<<1024, 256, 0, stream>>>(src, dst, cnt, outcnt);
    k_scan<<<1, 1024, 0, stream>>>(cnt, row_ptr, fillp);
    k_fill<<<1024, 256, 0, stream>>>(dst, fillp, eid);
    k_avg<<<(NN + 255) / 256, 256, 0, stream>>>(outcnt, avg_sum);
    k_tgt<<<64, 64, 0, stream>>>(tgt, etype, query_emb, tgt_q, efeat);
    k_eqg<<<32, 64, 0, stream>>>(tgt_q, eqp_w, eqp_b, eq_g);
    k_equery<<<8192, 256, 0, stream>>>(egid, eq_g, equery);
    k_pack_gru<<<dim3(16, 3), 256, 0, stream>>>(gru_wx, gru_wh, wpg);
    k_pack_lstm<<<dim3(16, 3), 256, 0, stream>>>(lstm_wx, lstm_wh, wpl);

    for (int l = 0; l < 3; l++) {
        k_gru<<<2000, 256, 0, stream>>>(src, etype, nfeat, equery, efeat,
            rel_w + (size_t)l * NR * 64, wpg + (size_t)l * 32768,
            gru_bx + (size_t)l * 192, gru_bh + (size_t)l * 192, msg);
        k_node<<<2500, 256, 0, stream>>>(row_ptr, eid, msg, avg_sum,
            pna_w + (size_t)l * 768 * 64, pna_b + (size_t)l * 64,
            ln_g + (size_t)l * 64, ln_b + (size_t)l * 64, nfeat, nfeat_new);
        k_lstm<<<2000, 256, 0, stream>>>(dst, nfeat_new, wpl + (size_t)l * 32768,
            lstm_b + (size_t)l * 256,
            ln_g + (size_t)l * 64, ln_b + (size_t)l * 64, efeat, equery);
        k_snap<<<64, 64, 0, stream>>>(tgt, src, efeat, equery, nfeat,
            jk_e + l * 4096, jk_q + l * 4096, jk_n + l * 4096);
    }

    k_jk<<<64, 64, 0, stream>>>(jk_e, jk_q, jk_n, ejk_w, ejk_b, qjk_w, qjk_b, njk_w, njk_b,
                                ejk_o, qjk_o, njk_o);
    k_final<<<32, 64, 0, stream>>>(ejk_o, qjk_o, njk_o, fc_w, fc_b, (float*)d_out);
}

// Round 4
// 1363.346 us; speedup vs baseline: 19.1182x; 1.0856x over previous
//
#include <hip/hip_runtime.h>
#include <math.h>

#define EN 256000
#define NN 40000
#define NR 474
#define EPS_ 1e-5f

typedef __attribute__((ext_vector_type(4))) float f4_t;
typedef __attribute__((ext_vector_type(8))) short bf8_t;
typedef __attribute__((ext_vector_type(4))) float facc_t;

__device__ __forceinline__ float sigm(float x) { return 1.f / (1.f + __expf(-x)); }
__device__ __forceinline__ float tanh_f(float x) { float e = __expf(2.f * x); return 1.f - 2.f / (e + 1.f); }

// one-time pack kernels use the exact RNE bit-twiddle (matches cvt_pk rounding)
__device__ __forceinline__ short f2bf(float f) {
    unsigned u = __float_as_uint(f);
    return (short)((u + 0x7FFFu + ((u >> 16) & 1u)) >> 16);
}
// hot-loop pack: hardware v_cvt_pk_bf16_f32 (2 floats -> 1 dword of 2 bf16)
__device__ __forceinline__ unsigned cvtpk(float lo, float hi) {
    unsigned r;
    asm("v_cvt_pk_bf16_f32 %0, %1, %2" : "=v"(r) : "v"(lo), "v"(hi));
    return r;
}
__device__ __forceinline__ bf8_t pack8(f4_t a, f4_t b) {
    union { unsigned u[4]; bf8_t v; } r;
    r.u[0] = cvtpk(a[0], a[1]);
    r.u[1] = cvtpk(a[2], a[3]);
    r.u[2] = cvtpk(b[0], b[1]);
    r.u[3] = cvtpk(b[2], b[3]);
    return r.v;
}

__device__ __forceinline__ void wave_ln(float v, float& mean, float& var) {
    float s = v, s2 = v * v;
    #pragma unroll
    for (int off = 32; off > 0; off >>= 1) { s += __shfl_xor(s, off, 64); s2 += __shfl_xor(s2, off, 64); }
    mean = s * (1.f / 64.f);
    var = s2 * (1.f / 64.f) - mean * mean;
}

// ---------------- init / graph prep ----------------

__global__ void k_init(float* efeat, float* nfeat, int* cnt, int* outcnt, float* avg_sum) {
    long total = (long)EN * 64;
    for (long i = blockIdx.x * (long)blockDim.x + threadIdx.x; i < total; i += (long)gridDim.x * blockDim.x) {
        efeat[i] = 0.f;
        if (i < (long)NN * 64) nfeat[i] = 0.f;
        if (i < NN) { cnt[i] = 0; outcnt[i] = 0; }
        if (i == 0) avg_sum[0] = 0.f;
    }
}

__global__ void k_count(const int* __restrict__ src, const int* __restrict__ dst, int* cnt, int* outcnt) {
    for (int e = blockIdx.x * blockDim.x + threadIdx.x; e < EN; e += gridDim.x * blockDim.x) {
        atomicAdd(&cnt[dst[e]], 1);
        atomicAdd(&outcnt[src[e]], 1);
    }
}

__global__ void k_scan(const int* __restrict__ cnt, int* __restrict__ row_ptr, int* __restrict__ fillp) {
    __shared__ int sums[1024];
    const int t = threadIdx.x;
    int s = 0;
    for (int i = 0; i < 40; i++) {
        int idx = t * 40 + i;
        if (idx < NN) s += cnt[idx];
    }
    sums[t] = s;
    __syncthreads();
    for (int off = 1; off < 1024; off <<= 1) {
        int v = (t >= off) ? sums[t - off] : 0;
        __syncthreads();
        sums[t] += v;
        __syncthreads();
    }
    int run = (t == 0) ? 0 : sums[t - 1];
    for (int i = 0; i < 40; i++) {
        int idx = t * 40 + i;
        if (idx < NN) { row_ptr[idx] = run; fillp[idx] = run; run += cnt[idx]; }
    }
    if (t == 1023) row_ptr[NN] = run;
}

__global__ void k_fill(const int* __restrict__ dst, int* fillp, int* eid) {
    for (int e = blockIdx.x * blockDim.x + threadIdx.x; e < EN; e += gridDim.x * blockDim.x) {
        int pos = atomicAdd(&fillp[dst[e]], 1);
        eid[pos] = e;
    }
}

__global__ void k_avg(const int* __restrict__ outcnt, float* __restrict__ avg_sum) {
    int n = blockIdx.x * blockDim.x + threadIdx.x;
    float v = 0.f;
    if (n < NN) v = logf((float)outcnt[n] + 1.f);
    #pragma unroll
    for (int off = 32; off > 0; off >>= 1) v += __shfl_xor(v, off, 64);
    if ((threadIdx.x & 63) == 0) atomicAdd(avg_sum, v);
}

__global__ void k_tgt(const int* __restrict__ tgt, const int* __restrict__ etype,
                      const float* __restrict__ query_emb, float* tgt_q, float* efeat) {
    int t = blockIdx.x, d = threadIdx.x;
    int e = tgt[t];
    int r = etype[e];
    float v = query_emb[r * 64 + d];
    tgt_q[t * 64 + d] = v;
    efeat[(size_t)e * 64 + d] = v;
}

__global__ void k_eqg(const float* __restrict__ tgt_q, const float* __restrict__ eqp_w,
                      const float* __restrict__ eqp_b, float* eq_g) {
    int g = blockIdx.x, d = threadIdx.x;
    float acc = eqp_b[d];
    for (int k = 0; k < 128; k++) {
        float a = tgt_q[(2 * g + (k >> 6)) * 64 + (k & 63)];
        acc += a * eqp_w[k * 64 + d];
    }
    eq_g[g * 64 + d] = acc;
}

__global__ void k_equery(const int* __restrict__ egid, const float* __restrict__ eq_g, float* equery) {
    long total = (long)EN * 64;
    for (long i = blockIdx.x * (long)blockDim.x + threadIdx.x; i < total; i += (long)gridDim.x * blockDim.x) {
        int e = (int)(i >> 6), d = (int)(i & 63);
        equery[i] = eq_g[egid[e] * 64 + d];
    }
}

// ---------------- weight packing for MFMA ----------------
// GRU/LSTM record layout: rec = (ks*16 + nt)*64 + lane; elem j=0..7:
//   W[k][c] with k = ks*32 + (lane>>4)*8 + j,  c = 16*nt + (lane&15)
// Column meaning: nt = w*4 + g; d = 16*w + (lane&15).

__global__ void k_pack_gru(const float* __restrict__ wx, const float* __restrict__ wh,
                           unsigned short* __restrict__ out) {
    int l = blockIdx.y;
    wx += (size_t)l * 64 * 192; wh += (size_t)l * 64 * 192; out += (size_t)l * 32768;
    for (int idx = blockIdx.x * blockDim.x + threadIdx.x; idx < 32768; idx += gridDim.x * blockDim.x) {
        int rec = idx >> 3, j = idx & 7;
        int lane = rec & 63, ksnt = rec >> 6;
        int nt = ksnt & 15, ks = ksnt >> 4;
        int k = ks * 32 + (lane >> 4) * 8 + j;
        int g = nt & 3, d = (nt >> 2) * 16 + (lane & 15);
        float v;
        if (g == 0)      v = k < 64 ? wx[k * 192 + d]        : wh[(k - 64) * 192 + d];
        else if (g == 1) v = k < 64 ? wx[k * 192 + 64 + d]   : wh[(k - 64) * 192 + 64 + d];
        else if (g == 2) v = k < 64 ? wx[k * 192 + 128 + d]  : 0.f;
        else             v = k < 64 ? 0.f                    : wh[(k - 64) * 192 + 128 + d];
        out[idx] = (unsigned short)f2bf(v);
    }
}

__global__ void k_pack_lstm(const float* __restrict__ wx, const float* __restrict__ wh,
                            unsigned short* __restrict__ out) {
    int l = blockIdx.y;
    wx += (size_t)l * 64 * 256; wh += (size_t)l * 64 * 256; out += (size_t)l * 32768;
    for (int idx = blockIdx.x * blockDim.x + threadIdx.x; idx < 32768; idx += gridDim.x * blockDim.x) {
        int rec = idx >> 3, j = idx & 7;
        int lane = rec & 63, ksnt = rec >> 6;
        int nt = ksnt & 15, ks = ksnt >> 4;
        int k = ks * 32 + (lane >> 4) * 8 + j;
        int g = nt & 3, d = (nt >> 2) * 16 + (lane & 15);
        float v = k < 64 ? wx[k * 256 + g * 64 + d] : wh[(k - 64) * 256 + g * 64 + d];
        out[idx] = (unsigned short)f2bf(v);
    }
}

// PNA pack: frag f = (ks*3 + y)*4 + w; rec = f*64 + lane; elem j:
//   B[k][n] with k = ks*32 + (lane>>4)*8 + j (k-interleave: k = dfeat*4 + sec),
//   n(d) = w*16 + (lane&15); source row = y*256 + sec*64 + dfeat.
__global__ void k_pack_pna(const float* __restrict__ pw, unsigned short* __restrict__ out) {
    int l = blockIdx.y;
    pw += (size_t)l * 768 * 64; out += (size_t)l * 49152;
    for (int idx = blockIdx.x * blockDim.x + threadIdx.x; idx < 49152; idx += gridDim.x * blockDim.x) {
        int rec = idx >> 3, j = idx & 7;
        int lane = rec & 63, f = rec >> 6;
        int w = f & 3, ys = f >> 2;
        int y = ys % 3, ks = ys / 3;
        int k = ks * 32 + (lane >> 4) * 8 + j;
        int sec = k & 3, dfeat = k >> 2;
        int d = w * 16 + (lane & 15);
        out[idx] = (unsigned short)f2bf(pw[(size_t)(y * 256 + sec * 64 + dfeat) * 64 + d]);
    }
}

// ---------------- per-layer kernels ----------------

__launch_bounds__(256)
__global__ void k_gru(const int* __restrict__ src, const int* __restrict__ etype,
                      const float* __restrict__ nfeat, const float* __restrict__ equery,
                      const float* __restrict__ efeat, const float* __restrict__ relw,
                      const unsigned short* __restrict__ wpack,
                      const float* __restrict__ bx, const float* __restrict__ bh,
                      float* __restrict__ msg) {
    const int lane = threadIdx.x & 63;
    const int w = threadIdx.x >> 6;
    const int row = lane & 15, kg = lane >> 4, dd = lane & 15;
    const int d = w * 16 + dd;
    bf8_t bf[4][4];
    #pragma unroll
    for (int ks = 0; ks < 4; ks++) {
        #pragma unroll
        for (int g = 0; g < 4; g++)
            bf[ks][g] = ((const bf8_t*)wpack)[(ks * 16 + w * 4 + g) * 64 + lane];
    }
    const float br_ = bx[d] + bh[d];
    const float bz_ = bx[64 + d] + bh[64 + d];
    const float bxn = bx[128 + d], bhn = bh[128 + d];
    for (int base = blockIdx.x * 16; base < EN; base += gridDim.x * 16) {
        const int e = base + row;
        const int s = src[e], ty = etype[e];
        bf8_t af[4];
        #pragma unroll
        for (int ks = 0; ks < 2; ks++) {
            const int kb = ks * 32 + kg * 8;
            f4_t n0 = *(const f4_t*)(nfeat + s * 64 + kb);
            f4_t n1 = *(const f4_t*)(nfeat + s * 64 + kb + 4);
            f4_t q0 = *(const f4_t*)(equery + (size_t)e * 64 + kb);
            f4_t q1 = *(const f4_t*)(equery + (size_t)e * 64 + kb + 4);
            af[ks] = pack8(n0 + q0, n1 + q1);
        }
        #pragma unroll
        for (int ks = 2; ks < 4; ks++) {
            const int kb = (ks - 2) * 32 + kg * 8;
            f4_t e0 = *(const f4_t*)(efeat + (size_t)e * 64 + kb);
            f4_t e1 = *(const f4_t*)(efeat + (size_t)e * 64 + kb + 4);
            f4_t r0 = *(const f4_t*)(relw + ty * 64 + kb);
            f4_t r1 = *(const f4_t*)(relw + ty * 64 + kb + 4);
            af[ks] = pack8(e0 * r0, e1 * r1);
        }
        facc_t ar = {0.f, 0.f, 0.f, 0.f}, az = ar, axn = ar, ahn = ar;
        #pragma unroll
        for (int ks = 0; ks < 4; ks++) {
            ar  = __builtin_amdgcn_mfma_f32_16x16x32_bf16(af[ks], bf[ks][0], ar, 0, 0, 0);
            az  = __builtin_amdgcn_mfma_f32_16x16x32_bf16(af[ks], bf[ks][1], az, 0, 0, 0);
            axn = __builtin_amdgcn_mfma_f32_16x16x32_bf16(af[ks], bf[ks][2], axn, 0, 0, 0);
            ahn = __builtin_amdgcn_mfma_f32_16x16x32_bf16(af[ks], bf[ks][3], ahn, 0, 0, 0);
        }
        #pragma unroll
        for (int rr = 0; rr < 4; rr++) {
            const int er = base + kg * 4 + rr;
            const float r_ = sigm(ar[rr] + br_);
            const float z_ = sigm(az[rr] + bz_);
            const float n_ = tanh_f(axn[rr] + bxn + r_ * (ahn[rr] + bhn));
            const int tyr = etype[er];
            const float h_ = efeat[(size_t)er * 64 + d] * relw[tyr * 64 + d];
            msg[(size_t)er * 64 + d] = (1.f - z_) * n_ + z_ * h_;
        }
    }
}

__launch_bounds__(256)
__global__ void k_lstm(const int* __restrict__ dst, const float* __restrict__ nfeat_new,
                       const unsigned short* __restrict__ wpack, const float* __restrict__ bb,
                       const float* __restrict__ g_ln, const float* __restrict__ b_ln,
                       float* __restrict__ efeat, float* __restrict__ equery) {
    __shared__ float red[4][16][4];
    const int lane = threadIdx.x & 63;
    const int w = threadIdx.x >> 6;
    const int row = lane & 15, kg = lane >> 4, dd = lane & 15;
    const int d = w * 16 + dd;
    bf8_t bf[4][4];
    #pragma unroll
    for (int ks = 0; ks < 4; ks++) {
        #pragma unroll
        for (int g = 0; g < 4; g++)
            bf[ks][g] = ((const bf8_t*)wpack)[(ks * 16 + w * 4 + g) * 64 + lane];
    }
    const float bi = bb[d], bfb = bb[64 + d], bg = bb[128 + d], bo = bb[192 + d];
    const float lg = g_ln[d], lb = b_ln[d];
    for (int base = blockIdx.x * 16; base < EN; base += gridDim.x * 16) {
        const int e = base + row;
        const int de = dst[e];
        bf8_t af[4];
        #pragma unroll
        for (int ks = 0; ks < 2; ks++) {
            const int kb = ks * 32 + kg * 8;
            f4_t v0 = *(const f4_t*)(nfeat_new + de * 64 + kb);
            f4_t v1 = *(const f4_t*)(nfeat_new + de * 64 + kb + 4);
            af[ks] = pack8(v0, v1);
        }
        #pragma unroll
        for (int ks = 2; ks < 4; ks++) {
            const int kb = (ks - 2) * 32 + kg * 8;
            f4_t v0 = *(const f4_t*)(efeat + (size_t)e * 64 + kb);
            f4_t v1 = *(const f4_t*)(efeat + (size_t)e * 64 + kb + 4);
            af[ks] = pack8(v0, v1);
        }
        facc_t ai = {0.f, 0.f, 0.f, 0.f}, af_ = ai, ag = ai, ao = ai;
        #pragma unroll
        for (int ks = 0; ks < 4; ks++) {
            ai  = __builtin_amdgcn_mfma_f32_16x16x32_bf16(af[ks], bf[ks][0], ai, 0, 0, 0);
            af_ = __builtin_amdgcn_mfma_f32_16x16x32_bf16(af[ks], bf[ks][1], af_, 0, 0, 0);
            ag  = __builtin_amdgcn_mfma_f32_16x16x32_bf16(af[ks], bf[ks][2], ag, 0, 0, 0);
            ao  = __builtin_amdgcn_mfma_f32_16x16x32_bf16(af[ks], bf[ks][3], ao, 0, 0, 0);
        }
        float hh[4], cc[4], eqs[4];
        #pragma unroll
        for (int rr = 0; rr < 4; rr++) {
            const int er = base + kg * 4 + rr;
            eqs[rr] = equery[(size_t)er * 64 + d];
            const float ci = sigm(ai[rr] + bi);
            const float cf = sigm(af_[rr] + bfb);
            const float cg = tanh_f(ag[rr] + bg);
            const float co = sigm(ao[rr] + bo);
            const float c_ = cf * eqs[rr] + ci * cg;
            cc[rr] = c_;
            hh[rr] = co * tanh_f(c_);
        }
        float hs[4], hs2[4], cs[4], cs2[4];
        #pragma unroll
        for (int rr = 0; rr < 4; rr++) { hs[rr] = hh[rr]; hs2[rr] = hh[rr] * hh[rr]; cs[rr] = cc[rr]; cs2[rr] = cc[rr] * cc[rr]; }
        #pragma unroll
        for (int off = 1; off < 16; off <<= 1) {
            #pragma unroll
            for (int rr = 0; rr < 4; rr++) {
                hs[rr] += __shfl_xor(hs[rr], off, 64);
                hs2[rr] += __shfl_xor(hs2[rr], off, 64);
                cs[rr] += __shfl_xor(cs[rr], off, 64);
                cs2[rr] += __shfl_xor(cs2[rr], off, 64);
            }
        }
        __syncthreads();
        if (dd == 0) {
            #pragma unroll
            for (int rr = 0; rr < 4; rr++) {
                red[w][kg * 4 + rr][0] = hs[rr];
                red[w][kg * 4 + rr][1] = hs2[rr];
                red[w][kg * 4 + rr][2] = cs[rr];
                red[w][kg * 4 + rr][3] = cs2[rr];
            }
        }
        __syncthreads();
        #pragma unroll
        for (int rr = 0; rr < 4; rr++) {
            const int el = kg * 4 + rr;
            float th = 0.f, th2 = 0.f, tc = 0.f, tc2 = 0.f;
            #pragma unroll
            for (int w2 = 0; w2 < 4; w2++) {
                th += red[w2][el][0]; th2 += red[w2][el][1];
                tc += red[w2][el][2]; tc2 += red[w2][el][3];
            }
            const float hm = th * (1.f / 64.f), hv = th2 * (1.f / 64.f) - hm * hm;
            const float cm = tc * (1.f / 64.f), cv = tc2 * (1.f / 64.f) - cm * cm;
            const int er = base + kg * 4 + rr;
            const size_t off = (size_t)er * 64 + d;
            efeat[off] = efeat[off] + (hh[rr] - hm) * rsqrtf(hv + EPS_) * lg + lb;
            equery[off] = eqs[rr] + (cc[rr] - cm) * rsqrtf(cv + EPS_) * lg + lb;
        }
    }
}

// k_node: block = 16 nodes. Phase A: each wave aggregates 4 nodes (lane = d).
// aggs written to LDS bf16, k-interleaved (k = d*4 + sec), stride 280.
// Phase B: MFMA aggs(16x256) @ [W0|W1|W2] per-wave N-slice, combine with samp/satt, LN.
__launch_bounds__(256)
__global__ void k_node(const int* __restrict__ row_ptr, const int* __restrict__ eid,
                       const float* __restrict__ msg, const float* __restrict__ avg_sum,
                       const unsigned short* __restrict__ wpack, const float* __restrict__ pb,
                       const float* __restrict__ g_ln, const float* __restrict__ b_ln,
                       float* __restrict__ nfeat, float* __restrict__ nfeat_new) {
    __shared__ unsigned short sAgg[16 * 280];
    __shared__ float sS[16], sT[16];
    __shared__ float sRed[4][16][2];
    const int lane = threadIdx.x & 63;
    const int w = threadIdx.x >> 6;
    const int base = blockIdx.x * 16;
    const float avg = avg_sum[0] * (1.f / (float)NN);

    // B preload: 24 frags (8 ksteps x 3 sections) for this wave's d-slice
    bf8_t bw[8][3];
    #pragma unroll
    for (int ks = 0; ks < 8; ks++) {
        #pragma unroll
        for (int y = 0; y < 3; y++)
            bw[ks][y] = ((const bf8_t*)wpack)[((ks * 3 + y) * 4 + w) * 64 + lane];
    }

    // ---- Phase A: aggregate 4 nodes per wave, lane = d ----
    float samp[4], satt[4];
    #pragma unroll
    for (int q = 0; q < 4; q++) {
        const int m = w * 4 + q;
        const int v = base + m;
        const int rs = row_ptr[v], re = row_ptr[v + 1];
        float s = 0.f, s2 = 0.f, mx = -INFINITY, mn = INFINITY;
        for (int i = rs; i < re; i++) {
            const int e = eid[i];
            const float mv = msg[(size_t)e * 64 + lane];
            s += mv; s2 += mv * mv; mx = fmaxf(mx, mv); mn = fminf(mn, mv);
        }
        const float deg = (float)(re - rs);
        const float dsafe = fmaxf(deg, 1.f);
        const float mean = s / dsafe;
        const float sq = s2 / dsafe;
        const bool has = (re - rs) > 0;
        const float amx = has ? mx : 0.f;
        const float amn = has ? mn : 0.f;
        const float astd = sqrtf(fmaxf(sq - mean * mean, 0.f) + EPS_);
        uint2 pk;
        pk.x = cvtpk(mean, amx);
        pk.y = cvtpk(amn, astd);
        *(uint2*)&sAgg[m * 280 + lane * 4] = pk;
        const float ld = logf(deg + 1.f);
        samp[q] = ld / avg;
        satt[q] = ld > 0.f ? avg / fmaxf(ld, EPS_) : 0.f;
    }
    if (lane == 0) {
        #pragma unroll
        for (int q = 0; q < 4; q++) { sS[w * 4 + q] = samp[q]; sT[w * 4 + q] = satt[q]; }
    }
    __syncthreads();

    // ---- Phase B: MFMA GEMM ----
    facc_t c0 = {0.f, 0.f, 0.f, 0.f}, c1 = c0, c2 = c0;
    const int arow = lane & 15, acol = (lane >> 4) * 8;
    #pragma unroll
    for (int ks = 0; ks < 8; ks++) {
        bf8_t af = *(const bf8_t*)&sAgg[arow * 280 + ks * 32 + acol];
        c0 = __builtin_amdgcn_mfma_f32_16x16x32_bf16(af, bw[ks][0], c0, 0, 0, 0);
        c1 = __builtin_amdgcn_mfma_f32_16x16x32_bf16(af, bw[ks][1], c1, 0, 0, 0);
        c2 = __builtin_amdgcn_mfma_f32_16x16x32_bf16(af, bw[ks][2], c2, 0, 0, 0);
    }

    const int d = w * 16 + (lane & 15);
    const float pbl = pb[d], lg = g_ln[d], lb = b_ln[d];
    float nf[4];
    #pragma unroll
    for (int rr = 0; rr < 4; rr++) {
        const int m = (lane >> 4) * 4 + rr;
        nf[rr] = pbl + c0[rr] + sS[m] * c1[rr] + sT[m] * c2[rr];
        nfeat_new[(size_t)(base + m) * 64 + d] = nf[rr];
    }
    // LN partial: reduce over the 16 d-values this wave holds per node
    float ps[4], ps2[4];
    #pragma unroll
    for (int rr = 0; rr < 4; rr++) { ps[rr] = nf[rr]; ps2[rr] = nf[rr] * nf[rr]; }
    #pragma unroll
    for (int off = 1; off < 16; off <<= 1) {
        #pragma unroll
        for (int rr = 0; rr < 4; rr++) {
            ps[rr] += __shfl_xor(ps[rr], off, 64);
            ps2[rr] += __shfl_xor(ps2[rr], off, 64);
        }
    }
    if ((lane & 15) == 0) {
        #pragma unroll
        for (int rr = 0; rr < 4; rr++) {
            const int m = (lane >> 4) * 4 + rr;
            sRed[w][m][0] = ps[rr];
            sRed[w][m][1] = ps2[rr];
        }
    }
    __syncthreads();
    #pragma unroll
    for (int rr = 0; rr < 4; rr++) {
        const int m = (lane >> 4) * 4 + rr;
        float ts = 0.f, ts2 = 0.f;
        #pragma unroll
        for (int w2 = 0; w2 < 4; w2++) { ts += sRed[w2][m][0]; ts2 += sRed[w2][m][1]; }
        const float mean = ts * (1.f / 64.f);
        const float var = ts2 * (1.f / 64.f) - mean * mean;
        const size_t off = (size_t)(base + m) * 64 + d;
        nfeat[off] += (nf[rr] - mean) * rsqrtf(var + EPS_) * lg + lb;
    }
}

__global__ void k_snap(const int* __restrict__ tgt, const int* __restrict__ src,
                       const float* __restrict__ efeat, const float* __restrict__ equery,
                       const float* __restrict__ nfeat,
                       float* jk_e, float* jk_q, float* jk_n) {
    int t = blockIdx.x, d = threadIdx.x;
    int e = tgt[t];
    jk_e[t * 64 + d] = efeat[(size_t)e * 64 + d];
    jk_q[t * 64 + d] = equery[(size_t)e * 64 + d];
    int v = src[e];
    jk_n[t * 64 + d] = nfeat[v * 64 + d];
}

// ---------------- output head ----------------

__global__ void k_jk(const float* __restrict__ jk_e, const float* __restrict__ jk_q, const float* __restrict__ jk_n,
                     const float* __restrict__ ejk_w, const float* __restrict__ ejk_b,
                     const float* __restrict__ qjk_w, const float* __restrict__ qjk_b,
                     const float* __restrict__ njk_w, const float* __restrict__ njk_b,
                     float* ejk_o, float* qjk_o, float* njk_o) {
    int t = blockIdx.x, d = threadIdx.x;
    float ae = ejk_b[d], aq = qjk_b[d], an_ = njk_b[d];
    for (int l = 0; l < 3; l++) {
        for (int dd = 0; dd < 64; dd++) {
            int k = l * 64 + dd;
            ae += jk_e[(l * 64 + t) * 64 + dd] * ejk_w[k * 64 + d];
            aq += jk_q[(l * 64 + t) * 64 + dd] * qjk_w[k * 64 + d];
            an_ += jk_n[(l * 64 + t) * 64 + dd] * njk_w[k * 64 + d];
        }
    }
    ejk_o[t * 64 + d] = ae;
    qjk_o[t * 64 + d] = aq;
    njk_o[t * 64 + d] = an_;
}

__global__ void k_final(const float* __restrict__ ejk_o, const float* __restrict__ qjk_o,
                        const float* __restrict__ njk_o,
                        const float* __restrict__ fc_w, const float* __restrict__ fc_b,
                        float* out) {
    int b = blockIdx.x, d = threadIdx.x;
    int t0 = 2 * b, t1 = 2 * b + 1;
    float r = ejk_o[t0 * 64 + d] * fc_w[d] + qjk_o[t0 * 64 + d] * fc_w[64 + d]
            + njk_o[t0 * 64 + d] * fc_w[128 + d] + njk_o[t1 * 64 + d] * fc_w[192 + d];
    float lf = ejk_o[t1 * 64 + d] * fc_w[d] + qjk_o[t1 * 64 + d] * fc_w[64 + d]
             + njk_o[t1 * 64 + d] * fc_w[128 + d] + njk_o[t0 * 64 + d] * fc_w[192 + d];
    #pragma unroll
    for (int off = 32; off > 0; off >>= 1) { r += __shfl_xor(r, off, 64); lf += __shfl_xor(lf, off, 64); }
    if (d == 0) out[b] = fmaxf(r + fc_b[0], lf + fc_b[0]);
}

// ---------------- host launcher ----------------

extern "C" void kernel_launch(void* const* d_in, const int* in_sizes, int n_in,
                              void* d_out, int out_size, void* d_ws, size_t ws_size,
                              hipStream_t stream) {
    const int* src   = (const int*)d_in[0];
    const int* dst   = (const int*)d_in[1];
    const int* etype = (const int*)d_in[2];
    const int* egid  = (const int*)d_in[3];
    const int* tgt   = (const int*)d_in[4];
    const float* query_emb = (const float*)d_in[6];
    const float* eqp_w = (const float*)d_in[7];
    const float* eqp_b = (const float*)d_in[8];
    const float* rel_w = (const float*)d_in[9];
    const float* gru_wx = (const float*)d_in[10];
    const float* gru_wh = (const float*)d_in[11];
    const float* gru_bx = (const float*)d_in[12];
    const float* gru_bh = (const float*)d_in[13];
    const float* pna_w = (const float*)d_in[14];
    const float* pna_b = (const float*)d_in[15];
    const float* lstm_wx = (const float*)d_in[16];
    const float* lstm_wh = (const float*)d_in[17];
    const float* lstm_b = (const float*)d_in[18];
    const float* ln_g = (const float*)d_in[19];
    const float* ln_b = (const float*)d_in[20];
    const float* ejk_w = (const float*)d_in[21];
    const float* ejk_b = (const float*)d_in[22];
    const float* njk_w = (const float*)d_in[23];
    const float* njk_b = (const float*)d_in[24];
    const float* qjk_w = (const float*)d_in[25];
    const float* qjk_b = (const float*)d_in[26];
    const float* fc_w = (const float*)d_in[27];
    const float* fc_b = (const float*)d_in[28];

    float* p = (float*)d_ws;
    float* equery = p;    p += (size_t)EN * 64;
    float* efeat = p;     p += (size_t)EN * 64;
    float* msg = p;       p += (size_t)EN * 64;
    float* nfeat = p;     p += (size_t)NN * 64;
    float* nfeat_new = p; p += (size_t)NN * 64;
    float* tgt_q = p;     p += 64 * 64;
    float* eq_g = p;      p += 32 * 64;
    float* jk_e = p;      p += 3 * 64 * 64;
    float* jk_q = p;      p += 3 * 64 * 64;
    float* jk_n = p;      p += 3 * 64 * 64;
    float* ejk_o = p;     p += 64 * 64;
    float* qjk_o = p;     p += 64 * 64;
    float* njk_o = p;     p += 64 * 64;
    float* avg_sum = p;   p += 64;
    unsigned short* wpg = (unsigned short*)p;   // 3*32768 bf16
    unsigned short* wpl = wpg + 3 * 32768;      // 3*32768 bf16
    unsigned short* wpp = wpl + 3 * 32768;      // 3*49152 bf16
    int* ip = (int*)(wpp + 3 * 49152);
    int* row_ptr = ip; ip += NN + 1;
    int* fillp = ip;   ip += NN;
    int* cnt = ip;     ip += NN;
    int* outcnt = ip;  ip += NN;
    int* eid = ip;     ip += EN;
    if ((size_t)((char*)ip - (char*)d_ws) > ws_size) return;

    k_init<<<4096, 256, 0, stream>>>(efeat, nfeat, cnt, outcnt, avg_sum);
    k_count<<<1024, 256, 0, stream>>>(src, dst, cnt, outcnt);
    k_scan<<<1, 1024, 0, stream>>>(cnt, row_ptr, fillp);
    k_fill<<<1024, 256, 0, stream>>>(dst, fillp, eid);
    k_avg<<<(NN + 255) / 256, 256, 0, stream>>>(outcnt, avg_sum);
    k_tgt<<<64, 64, 0, stream>>>(tgt, etype, query_emb, tgt_q, efeat);
    k_eqg<<<32, 64, 0, stream>>>(tgt_q, eqp_w, eqp_b, eq_g);
    k_equery<<<8192, 256, 0, stream>>>(egid, eq_g, equery);
    k_pack_gru<<<dim3(16, 3), 256, 0, stream>>>(gru_wx, gru_wh, wpg);
    k_pack_lstm<<<dim3(16, 3), 256, 0, stream>>>(lstm_wx, lstm_wh, wpl);
    k_pack_pna<<<dim3(24, 3), 256, 0, stream>>>(pna_w, wpp);

    for (int l = 0; l < 3; l++) {
        k_gru<<<2000, 256, 0, stream>>>(src, etype, nfeat, equery, efeat,
            rel_w + (size_t)l * NR * 64, wpg + (size_t)l * 32768,
            gru_bx + (size_t)l * 192, gru_bh + (size_t)l * 192, msg);
        k_node<<<NN / 16, 256, 0, stream>>>(row_ptr, eid, msg, avg_sum,
            wpp + (size_t)l * 49152, pna_b + (size_t)l * 64,
            ln_g + (size_t)l * 64, ln_b + (size_t)l * 64, nfeat, nfeat_new);
        k_lstm<<<2000, 256, 0, stream>>>(dst, nfeat_new, wpl + (size_t)l * 32768,
            lstm_b + (size_t)l * 256,
            ln_g + (size_t)l * 64, ln_b + (size_t)l * 64, efeat, equery);
        k_snap<<<64, 64, 0, stream>>>(tgt, src, efeat, equery, nfeat,
            jk_e + l * 4096, jk_q + l * 4096, jk_n + l * 4096);
    }

    k_jk<<<64, 64, 0, stream>>>(jk_e, jk_q, jk_n, ejk_w, ejk_b, qjk_w, qjk_b, njk_w, njk_b,
                                ejk_o, qjk_o, njk_o);
    k_final<<<32, 64, 0, stream>>>(ejk_o, qjk_o, njk_o, fc_w, fc_b, (float*)d_out);
}

// Round 5
// 1133.225 us; speedup vs baseline: 23.0005x; 1.2031x over previous
//
#include <hip/hip_runtime.h>
#include <math.h>

#define EN 256000
#define NN 40000
#define NR 474
#define EPS_ 1e-5f

typedef __attribute__((ext_vector_type(4))) float f4_t;
typedef __attribute__((ext_vector_type(8))) short bf8_t;
typedef __attribute__((ext_vector_type(4))) float facc_t;

__device__ __forceinline__ float sigm(float x) { return 1.f / (1.f + __expf(-x)); }
__device__ __forceinline__ float tanh_f(float x) { float e = __expf(2.f * x); return 1.f - 2.f / (e + 1.f); }

// one-time pack kernels use the exact RNE bit-twiddle (matches cvt_pk rounding)
__device__ __forceinline__ short f2bf(float f) {
    unsigned u = __float_as_uint(f);
    return (short)((u + 0x7FFFu + ((u >> 16) & 1u)) >> 16);
}
// hot-loop pack: hardware v_cvt_pk_bf16_f32 (2 floats -> 1 dword of 2 bf16)
__device__ __forceinline__ unsigned cvtpk(float lo, float hi) {
    unsigned r;
    asm("v_cvt_pk_bf16_f32 %0, %1, %2" : "=v"(r) : "v"(lo), "v"(hi));
    return r;
}
__device__ __forceinline__ bf8_t pack8(f4_t a, f4_t b) {
    union { unsigned u[4]; bf8_t v; } r;
    r.u[0] = cvtpk(a[0], a[1]);
    r.u[1] = cvtpk(a[2], a[3]);
    r.u[2] = cvtpk(b[0], b[1]);
    r.u[3] = cvtpk(b[2], b[3]);
    return r.v;
}

__device__ __forceinline__ void wave_ln(float v, float& mean, float& var) {
    float s = v, s2 = v * v;
    #pragma unroll
    for (int off = 32; off > 0; off >>= 1) { s += __shfl_xor(s, off, 64); s2 += __shfl_xor(s2, off, 64); }
    mean = s * (1.f / 64.f);
    var = s2 * (1.f / 64.f) - mean * mean;
}

// ---------------- init / graph prep ----------------

__global__ void k_init(float* efeat, float* nfeat, int* cnt, int* outcnt, float* avg_sum) {
    long total = (long)EN * 64;
    for (long i = blockIdx.x * (long)blockDim.x + threadIdx.x; i < total; i += (long)gridDim.x * blockDim.x) {
        efeat[i] = 0.f;
        if (i < (long)NN * 64) nfeat[i] = 0.f;
        if (i < NN) { cnt[i] = 0; outcnt[i] = 0; }
        if (i == 0) avg_sum[0] = 0.f;
    }
}

__global__ void k_count(const int* __restrict__ src, const int* __restrict__ dst, int* cnt, int* outcnt) {
    for (int e = blockIdx.x * blockDim.x + threadIdx.x; e < EN; e += gridDim.x * blockDim.x) {
        atomicAdd(&cnt[dst[e]], 1);
        atomicAdd(&outcnt[src[e]], 1);
    }
}

__global__ void k_scan(const int* __restrict__ cnt, int* __restrict__ row_ptr, int* __restrict__ fillp) {
    __shared__ int sums[1024];
    const int t = threadIdx.x;
    int s = 0;
    for (int i = 0; i < 40; i++) {
        int idx = t * 40 + i;
        if (idx < NN) s += cnt[idx];
    }
    sums[t] = s;
    __syncthreads();
    for (int off = 1; off < 1024; off <<= 1) {
        int v = (t >= off) ? sums[t - off] : 0;
        __syncthreads();
        sums[t] += v;
        __syncthreads();
    }
    int run = (t == 0) ? 0 : sums[t - 1];
    for (int i = 0; i < 40; i++) {
        int idx = t * 40 + i;
        if (idx < NN) { row_ptr[idx] = run; fillp[idx] = run; run += cnt[idx]; }
    }
    if (t == 1023) row_ptr[NN] = run;
}

__global__ void k_fill(const int* __restrict__ dst, int* fillp, int* eid) {
    for (int e = blockIdx.x * blockDim.x + threadIdx.x; e < EN; e += gridDim.x * blockDim.x) {
        int pos = atomicAdd(&fillp[dst[e]], 1);
        eid[pos] = e;
    }
}

__global__ void k_avg(const int* __restrict__ outcnt, float* __restrict__ avg_sum) {
    int n = blockIdx.x * blockDim.x + threadIdx.x;
    float v = 0.f;
    if (n < NN) v = logf((float)outcnt[n] + 1.f);
    #pragma unroll
    for (int off = 32; off > 0; off >>= 1) v += __shfl_xor(v, off, 64);
    if ((threadIdx.x & 63) == 0) atomicAdd(avg_sum, v);
}

__global__ void k_tgt(const int* __restrict__ tgt, const int* __restrict__ etype,
                      const float* __restrict__ query_emb, float* tgt_q, float* efeat) {
    int t = blockIdx.x, d = threadIdx.x;
    int e = tgt[t];
    int r = etype[e];
    float v = query_emb[r * 64 + d];
    tgt_q[t * 64 + d] = v;
    efeat[(size_t)e * 64 + d] = v;
}

__global__ void k_eqg(const float* __restrict__ tgt_q, const float* __restrict__ eqp_w,
                      const float* __restrict__ eqp_b, float* eq_g) {
    int g = blockIdx.x, d = threadIdx.x;
    float acc = eqp_b[d];
    for (int k = 0; k < 128; k++) {
        float a = tgt_q[(2 * g + (k >> 6)) * 64 + (k & 63)];
        acc += a * eqp_w[k * 64 + d];
    }
    eq_g[g * 64 + d] = acc;
}

__global__ void k_equery(const int* __restrict__ egid, const float* __restrict__ eq_g, float* equery) {
    long total = (long)EN * 64;
    for (long i = blockIdx.x * (long)blockDim.x + threadIdx.x; i < total; i += (long)gridDim.x * blockDim.x) {
        int e = (int)(i >> 6), d = (int)(i & 63);
        equery[i] = eq_g[egid[e] * 64 + d];
    }
}

// ---------------- weight packing for MFMA ----------------
// GRU/LSTM record layout: rec = (ks*16 + nt)*64 + lane; elem j=0..7:
//   W[k][c] with k = ks*32 + (lane>>4)*8 + j,  c = 16*nt + (lane&15)
// Column meaning: nt = w*4 + g; d = 16*w + (lane&15).

__global__ void k_pack_gru(const float* __restrict__ wx, const float* __restrict__ wh,
                           unsigned short* __restrict__ out) {
    int l = blockIdx.y;
    wx += (size_t)l * 64 * 192; wh += (size_t)l * 64 * 192; out += (size_t)l * 32768;
    for (int idx = blockIdx.x * blockDim.x + threadIdx.x; idx < 32768; idx += gridDim.x * blockDim.x) {
        int rec = idx >> 3, j = idx & 7;
        int lane = rec & 63, ksnt = rec >> 6;
        int nt = ksnt & 15, ks = ksnt >> 4;
        int k = ks * 32 + (lane >> 4) * 8 + j;
        int g = nt & 3, d = (nt >> 2) * 16 + (lane & 15);
        float v;
        if (g == 0)      v = k < 64 ? wx[k * 192 + d]        : wh[(k - 64) * 192 + d];
        else if (g == 1) v = k < 64 ? wx[k * 192 + 64 + d]   : wh[(k - 64) * 192 + 64 + d];
        else if (g == 2) v = k < 64 ? wx[k * 192 + 128 + d]  : 0.f;
        else             v = k < 64 ? 0.f                    : wh[(k - 64) * 192 + 128 + d];
        out[idx] = (unsigned short)f2bf(v);
    }
}

__global__ void k_pack_lstm(const float* __restrict__ wx, const float* __restrict__ wh,
                            unsigned short* __restrict__ out) {
    int l = blockIdx.y;
    wx += (size_t)l * 64 * 256; wh += (size_t)l * 64 * 256; out += (size_t)l * 32768;
    for (int idx = blockIdx.x * blockDim.x + threadIdx.x; idx < 32768; idx += gridDim.x * blockDim.x) {
        int rec = idx >> 3, j = idx & 7;
        int lane = rec & 63, ksnt = rec >> 6;
        int nt = ksnt & 15, ks = ksnt >> 4;
        int k = ks * 32 + (lane >> 4) * 8 + j;
        int g = nt & 3, d = (nt >> 2) * 16 + (lane & 15);
        float v = k < 64 ? wx[k * 256 + g * 64 + d] : wh[(k - 64) * 256 + g * 64 + d];
        out[idx] = (unsigned short)f2bf(v);
    }
}

// PNA pack: frag f = (ks*3 + y)*4 + w; rec = f*64 + lane; elem j:
//   B[k][n] with k = ks*32 + (lane>>4)*8 + j (k-interleave: k = dfeat*4 + sec),
//   n(d) = w*16 + (lane&15); source row = y*256 + sec*64 + dfeat.
__global__ void k_pack_pna(const float* __restrict__ pw, unsigned short* __restrict__ out) {
    int l = blockIdx.y;
    pw += (size_t)l * 768 * 64; out += (size_t)l * 49152;
    for (int idx = blockIdx.x * blockDim.x + threadIdx.x; idx < 49152; idx += gridDim.x * blockDim.x) {
        int rec = idx >> 3, j = idx & 7;
        int lane = rec & 63, f = rec >> 6;
        int w = f & 3, ys = f >> 2;
        int y = ys % 3, ks = ys / 3;
        int k = ks * 32 + (lane >> 4) * 8 + j;
        int sec = k & 3, dfeat = k >> 2;
        int d = w * 16 + (lane & 15);
        out[idx] = (unsigned short)f2bf(pw[(size_t)(y * 256 + sec * 64 + dfeat) * 64 + d]);
    }
}

// ---------------- per-layer edge kernels ----------------
// New structure: 512-thread blocks; full weight pack (64 KB) staged in LDS once;
// each wave owns independent 16-edge chunks end-to-end (all 64 d, all gates),
// iterating 4 d-slices sequentially. Zero barriers in the main loop; LSTM LN is
// wave-local (per-edge running sums + 4-step butterfly).

__launch_bounds__(512, 4)
__global__ void k_gru(const int* __restrict__ src, const int* __restrict__ etype,
                      const float* __restrict__ nfeat, const float* __restrict__ equery,
                      const float* __restrict__ efeat, const float* __restrict__ relw,
                      const unsigned short* __restrict__ wpack,
                      const float* __restrict__ bx, const float* __restrict__ bh,
                      float* __restrict__ msg) {
    __shared__ unsigned short sW[32768];
    const int tid = threadIdx.x;
    const int lane = tid & 63;
    const int wv = tid >> 6;
    {
        const uint4* gsrc = (const uint4*)wpack;
        uint4* ldst = (uint4*)sW;
        #pragma unroll
        for (int i = 0; i < 8; i++) ldst[tid + i * 512] = gsrc[tid + i * 512];
    }
    __syncthreads();

    const int row = lane & 15, kg = lane >> 4;
    // per-lane biases for each slice w: d = w*16 + (lane&15)
    float br_[4], bz_[4], bxn_[4], bhn_[4];
    #pragma unroll
    for (int w = 0; w < 4; w++) {
        const int d = w * 16 + row;
        br_[w] = bx[d] + bh[d];
        bz_[w] = bx[64 + d] + bh[64 + d];
        bxn_[w] = bx[128 + d];
        bhn_[w] = bh[128 + d];
    }

    for (int chunk = blockIdx.x * 8 + wv; chunk < EN / 16; chunk += gridDim.x * 8) {
        const int base = chunk * 16;
        const int e = base + row;
        const int s = src[e], ty = etype[e];
        bf8_t af[4];
        #pragma unroll
        for (int ks = 0; ks < 2; ks++) {
            const int kb = ks * 32 + kg * 8;
            f4_t n0 = *(const f4_t*)(nfeat + s * 64 + kb);
            f4_t n1 = *(const f4_t*)(nfeat + s * 64 + kb + 4);
            f4_t q0 = *(const f4_t*)(equery + (size_t)e * 64 + kb);
            f4_t q1 = *(const f4_t*)(equery + (size_t)e * 64 + kb + 4);
            af[ks] = pack8(n0 + q0, n1 + q1);
        }
        #pragma unroll
        for (int ks = 2; ks < 4; ks++) {
            const int kb = (ks - 2) * 32 + kg * 8;
            f4_t e0 = *(const f4_t*)(efeat + (size_t)e * 64 + kb);
            f4_t e1 = *(const f4_t*)(efeat + (size_t)e * 64 + kb + 4);
            f4_t r0 = *(const f4_t*)(relw + ty * 64 + kb);
            f4_t r1 = *(const f4_t*)(relw + ty * 64 + kb + 4);
            af[ks] = pack8(e0 * r0, e1 * r1);
        }
        // per-lane output edges and their types
        int ers[4], tys[4];
        #pragma unroll
        for (int rr = 0; rr < 4; rr++) { ers[rr] = base + kg * 4 + rr; tys[rr] = etype[ers[rr]]; }

        #pragma unroll
        for (int w = 0; w < 4; w++) {
            facc_t ar = {0.f, 0.f, 0.f, 0.f}, az = ar, axn = ar, ahn = ar;
            #pragma unroll
            for (int ks = 0; ks < 4; ks++) {
                const int rb = (ks * 16 + w * 4) * 512 + lane * 8;
                bf8_t b0 = *(const bf8_t*)&sW[rb];
                bf8_t b1 = *(const bf8_t*)&sW[rb + 512];
                bf8_t b2 = *(const bf8_t*)&sW[rb + 1024];
                bf8_t b3 = *(const bf8_t*)&sW[rb + 1536];
                ar  = __builtin_amdgcn_mfma_f32_16x16x32_bf16(af[ks], b0, ar, 0, 0, 0);
                az  = __builtin_amdgcn_mfma_f32_16x16x32_bf16(af[ks], b1, az, 0, 0, 0);
                axn = __builtin_amdgcn_mfma_f32_16x16x32_bf16(af[ks], b2, axn, 0, 0, 0);
                ahn = __builtin_amdgcn_mfma_f32_16x16x32_bf16(af[ks], b3, ahn, 0, 0, 0);
            }
            const int d = w * 16 + row;
            #pragma unroll
            for (int rr = 0; rr < 4; rr++) {
                const float r_ = sigm(ar[rr] + br_[w]);
                const float z_ = sigm(az[rr] + bz_[w]);
                const float n_ = tanh_f(axn[rr] + bxn_[w] + r_ * (ahn[rr] + bhn_[w]));
                const float h_ = efeat[(size_t)ers[rr] * 64 + d] * relw[tys[rr] * 64 + d];
                msg[(size_t)ers[rr] * 64 + d] = (1.f - z_) * n_ + z_ * h_;
            }
        }
    }
}

__launch_bounds__(512, 4)
__global__ void k_lstm(const int* __restrict__ dst, const float* __restrict__ nfeat_new,
                       const unsigned short* __restrict__ wpack, const float* __restrict__ bb,
                       const float* __restrict__ g_ln, const float* __restrict__ b_ln,
                       float* __restrict__ efeat, float* __restrict__ equery) {
    __shared__ unsigned short sW[32768];
    const int tid = threadIdx.x;
    const int lane = tid & 63;
    const int wv = tid >> 6;
    {
        const uint4* gsrc = (const uint4*)wpack;
        uint4* ldst = (uint4*)sW;
        #pragma unroll
        for (int i = 0; i < 8; i++) ldst[tid + i * 512] = gsrc[tid + i * 512];
    }
    __syncthreads();

    const int row = lane & 15, kg = lane >> 4;

    for (int chunk = blockIdx.x * 8 + wv; chunk < EN / 16; chunk += gridDim.x * 8) {
        const int base = chunk * 16;
        const int e = base + row;
        const int de = dst[e];
        bf8_t af[4];
        #pragma unroll
        for (int ks = 0; ks < 2; ks++) {
            const int kb = ks * 32 + kg * 8;
            f4_t v0 = *(const f4_t*)(nfeat_new + de * 64 + kb);
            f4_t v1 = *(const f4_t*)(nfeat_new + de * 64 + kb + 4);
            af[ks] = pack8(v0, v1);
        }
        #pragma unroll
        for (int ks = 2; ks < 4; ks++) {
            const int kb = (ks - 2) * 32 + kg * 8;
            f4_t v0 = *(const f4_t*)(efeat + (size_t)e * 64 + kb);
            f4_t v1 = *(const f4_t*)(efeat + (size_t)e * 64 + kb + 4);
            af[ks] = pack8(v0, v1);
        }
        int ers[4];
        #pragma unroll
        for (int rr = 0; rr < 4; rr++) ers[rr] = base + kg * 4 + rr;

        float hh[4][4], cc[4][4];
        float sh[4] = {0, 0, 0, 0}, sh2[4] = {0, 0, 0, 0};
        float sc[4] = {0, 0, 0, 0}, sc2[4] = {0, 0, 0, 0};

        #pragma unroll
        for (int w = 0; w < 4; w++) {
            facc_t ai = {0.f, 0.f, 0.f, 0.f}, afv = ai, ag = ai, ao = ai;
            #pragma unroll
            for (int ks = 0; ks < 4; ks++) {
                const int rb = (ks * 16 + w * 4) * 512 + lane * 8;
                bf8_t b0 = *(const bf8_t*)&sW[rb];
                bf8_t b1 = *(const bf8_t*)&sW[rb + 512];
                bf8_t b2 = *(const bf8_t*)&sW[rb + 1024];
                bf8_t b3 = *(const bf8_t*)&sW[rb + 1536];
                ai  = __builtin_amdgcn_mfma_f32_16x16x32_bf16(af[ks], b0, ai, 0, 0, 0);
                afv = __builtin_amdgcn_mfma_f32_16x16x32_bf16(af[ks], b1, afv, 0, 0, 0);
                ag  = __builtin_amdgcn_mfma_f32_16x16x32_bf16(af[ks], b2, ag, 0, 0, 0);
                ao  = __builtin_amdgcn_mfma_f32_16x16x32_bf16(af[ks], b3, ao, 0, 0, 0);
            }
            const int d = w * 16 + row;
            const float bi = bb[d], bf_ = bb[64 + d], bg = bb[128 + d], bo = bb[192 + d];
            #pragma unroll
            for (int rr = 0; rr < 4; rr++) {
                const float eq = equery[(size_t)ers[rr] * 64 + d];
                const float ci = sigm(ai[rr] + bi);
                const float cf = sigm(afv[rr] + bf_);
                const float cg = tanh_f(ag[rr] + bg);
                const float co = sigm(ao[rr] + bo);
                const float c_ = cf * eq + ci * cg;
                const float h_ = co * tanh_f(c_);
                hh[w][rr] = h_; cc[w][rr] = c_;
                sh[rr] += h_; sh2[rr] += h_ * h_;
                sc[rr] += c_; sc2[rr] += c_ * c_;
            }
        }
        // wave-local LN reduce: sum over the 16 lanes sharing each edge group
        #pragma unroll
        for (int off = 1; off < 16; off <<= 1) {
            #pragma unroll
            for (int rr = 0; rr < 4; rr++) {
                sh[rr] += __shfl_xor(sh[rr], off, 64);
                sh2[rr] += __shfl_xor(sh2[rr], off, 64);
                sc[rr] += __shfl_xor(sc[rr], off, 64);
                sc2[rr] += __shfl_xor(sc2[rr], off, 64);
            }
        }
        float hm[4], hrs[4], cm[4], crs[4];
        #pragma unroll
        for (int rr = 0; rr < 4; rr++) {
            hm[rr] = sh[rr] * (1.f / 64.f);
            hrs[rr] = rsqrtf(sh2[rr] * (1.f / 64.f) - hm[rr] * hm[rr] + EPS_);
            cm[rr] = sc[rr] * (1.f / 64.f);
            crs[rr] = rsqrtf(sc2[rr] * (1.f / 64.f) - cm[rr] * cm[rr] + EPS_);
        }
        #pragma unroll
        for (int w = 0; w < 4; w++) {
            const int d = w * 16 + row;
            const float lg = g_ln[d], lb = b_ln[d];
            #pragma unroll
            for (int rr = 0; rr < 4; rr++) {
                const size_t off = (size_t)ers[rr] * 64 + d;
                const float efo = efeat[off];
                const float eqo = equery[off];
                efeat[off] = efo + (hh[w][rr] - hm[rr]) * hrs[rr] * lg + lb;
                equery[off] = eqo + (cc[w][rr] - cm[rr]) * crs[rr] * lg + lb;
            }
        }
    }
}

// k_node: block = 16 nodes. Phase A: each wave aggregates 4 nodes (lane = d).
// aggs written to LDS bf16, k-interleaved (k = d*4 + sec), stride 280.
// Phase B: MFMA aggs(16x256) @ [W0|W1|W2] per-wave N-slice, combine with samp/satt, LN.
__launch_bounds__(256)
__global__ void k_node(const int* __restrict__ row_ptr, const int* __restrict__ eid,
                       const float* __restrict__ msg, const float* __restrict__ avg_sum,
                       const unsigned short* __restrict__ wpack, const float* __restrict__ pb,
                       const float* __restrict__ g_ln, const float* __restrict__ b_ln,
                       float* __restrict__ nfeat, float* __restrict__ nfeat_new) {
    __shared__ unsigned short sAgg[16 * 280];
    __shared__ float sS[16], sT[16];
    __shared__ float sRed[4][16][2];
    const int lane = threadIdx.x & 63;
    const int w = threadIdx.x >> 6;
    const int base = blockIdx.x * 16;
    const float avg = avg_sum[0] * (1.f / (float)NN);

    bf8_t bw[8][3];
    #pragma unroll
    for (int ks = 0; ks < 8; ks++) {
        #pragma unroll
        for (int y = 0; y < 3; y++)
            bw[ks][y] = ((const bf8_t*)wpack)[((ks * 3 + y) * 4 + w) * 64 + lane];
    }

    float samp[4], satt[4];
    #pragma unroll
    for (int q = 0; q < 4; q++) {
        const int m = w * 4 + q;
        const int v = base + m;
        const int rs = row_ptr[v], re = row_ptr[v + 1];
        float s = 0.f, s2 = 0.f, mx = -INFINITY, mn = INFINITY;
        for (int i = rs; i < re; i++) {
            const int e = eid[i];
            const float mv = msg[(size_t)e * 64 + lane];
            s += mv; s2 += mv * mv; mx = fmaxf(mx, mv); mn = fminf(mn, mv);
        }
        const float deg = (float)(re - rs);
        const float dsafe = fmaxf(deg, 1.f);
        const float mean = s / dsafe;
        const float sq = s2 / dsafe;
        const bool has = (re - rs) > 0;
        const float amx = has ? mx : 0.f;
        const float amn = has ? mn : 0.f;
        const float astd = sqrtf(fmaxf(sq - mean * mean, 0.f) + EPS_);
        uint2 pk;
        pk.x = cvtpk(mean, amx);
        pk.y = cvtpk(amn, astd);
        *(uint2*)&sAgg[m * 280 + lane * 4] = pk;
        const float ld = logf(deg + 1.f);
        samp[q] = ld / avg;
        satt[q] = ld > 0.f ? avg / fmaxf(ld, EPS_) : 0.f;
    }
    if (lane == 0) {
        #pragma unroll
        for (int q = 0; q < 4; q++) { sS[w * 4 + q] = samp[q]; sT[w * 4 + q] = satt[q]; }
    }
    __syncthreads();

    facc_t c0 = {0.f, 0.f, 0.f, 0.f}, c1 = c0, c2 = c0;
    const int arow = lane & 15, acol = (lane >> 4) * 8;
    #pragma unroll
    for (int ks = 0; ks < 8; ks++) {
        bf8_t af = *(const bf8_t*)&sAgg[arow * 280 + ks * 32 + acol];
        c0 = __builtin_amdgcn_mfma_f32_16x16x32_bf16(af, bw[ks][0], c0, 0, 0, 0);
        c1 = __builtin_amdgcn_mfma_f32_16x16x32_bf16(af, bw[ks][1], c1, 0, 0, 0);
        c2 = __builtin_amdgcn_mfma_f32_16x16x32_bf16(af, bw[ks][2], c2, 0, 0, 0);
    }

    const int d = w * 16 + (lane & 15);
    const float pbl = pb[d], lg = g_ln[d], lb = b_ln[d];
    float nf[4];
    #pragma unroll
    for (int rr = 0; rr < 4; rr++) {
        const int m = (lane >> 4) * 4 + rr;
        nf[rr] = pbl + c0[rr] + sS[m] * c1[rr] + sT[m] * c2[rr];
        nfeat_new[(size_t)(base + m) * 64 + d] = nf[rr];
    }
    float ps[4], ps2[4];
    #pragma unroll
    for (int rr = 0; rr < 4; rr++) { ps[rr] = nf[rr]; ps2[rr] = nf[rr] * nf[rr]; }
    #pragma unroll
    for (int off = 1; off < 16; off <<= 1) {
        #pragma unroll
        for (int rr = 0; rr < 4; rr++) {
            ps[rr] += __shfl_xor(ps[rr], off, 64);
            ps2[rr] += __shfl_xor(ps2[rr], off, 64);
        }
    }
    if ((lane & 15) == 0) {
        #pragma unroll
        for (int rr = 0; rr < 4; rr++) {
            const int m = (lane >> 4) * 4 + rr;
            sRed[w][m][0] = ps[rr];
            sRed[w][m][1] = ps2[rr];
        }
    }
    __syncthreads();
    #pragma unroll
    for (int rr = 0; rr < 4; rr++) {
        const int m = (lane >> 4) * 4 + rr;
        float ts = 0.f, ts2 = 0.f;
        #pragma unroll
        for (int w2 = 0; w2 < 4; w2++) { ts += sRed[w2][m][0]; ts2 += sRed[w2][m][1]; }
        const float mean = ts * (1.f / 64.f);
        const float var = ts2 * (1.f / 64.f) - mean * mean;
        const size_t off = (size_t)(base + m) * 64 + d;
        nfeat[off] += (nf[rr] - mean) * rsqrtf(var + EPS_) * lg + lb;
    }
}

__global__ void k_snap(const int* __restrict__ tgt, const int* __restrict__ src,
                       const float* __restrict__ efeat, const float* __restrict__ equery,
                       const float* __restrict__ nfeat,
                       float* jk_e, float* jk_q, float* jk_n) {
    int t = blockIdx.x, d = threadIdx.x;
    int e = tgt[t];
    jk_e[t * 64 + d] = efeat[(size_t)e * 64 + d];
    jk_q[t * 64 + d] = equery[(size_t)e * 64 + d];
    int v = src[e];
    jk_n[t * 64 + d] = nfeat[v * 64 + d];
}

// ---------------- output head ----------------

__global__ void k_jk(const float* __restrict__ jk_e, const float* __restrict__ jk_q, const float* __restrict__ jk_n,
                     const float* __restrict__ ejk_w, const float* __restrict__ ejk_b,
                     const float* __restrict__ qjk_w, const float* __restrict__ qjk_b,
                     const float* __restrict__ njk_w, const float* __restrict__ njk_b,
                     float* ejk_o, float* qjk_o, float* njk_o) {
    int t = blockIdx.x, d = threadIdx.x;
    float ae = ejk_b[d], aq = qjk_b[d], an_ = njk_b[d];
    for (int l = 0; l < 3; l++) {
        for (int dd = 0; dd < 64; dd++) {
            int k = l * 64 + dd;
            ae += jk_e[(l * 64 + t) * 64 + dd] * ejk_w[k * 64 + d];
            aq += jk_q[(l * 64 + t) * 64 + dd] * qjk_w[k * 64 + d];
            an_ += jk_n[(l * 64 + t) * 64 + dd] * njk_w[k * 64 + d];
        }
    }
    ejk_o[t * 64 + d] = ae;
    qjk_o[t * 64 + d] = aq;
    njk_o[t * 64 + d] = an_;
}

__global__ void k_final(const float* __restrict__ ejk_o, const float* __restrict__ qjk_o,
                        const float* __restrict__ njk_o,
                        const float* __restrict__ fc_w, const float* __restrict__ fc_b,
                        float* out) {
    int b = blockIdx.x, d = threadIdx.x;
    int t0 = 2 * b, t1 = 2 * b + 1;
    float r = ejk_o[t0 * 64 + d] * fc_w[d] + qjk_o[t0 * 64 + d] * fc_w[64 + d]
            + njk_o[t0 * 64 + d] * fc_w[128 + d] + njk_o[t1 * 64 + d] * fc_w[192 + d];
    float lf = ejk_o[t1 * 64 + d] * fc_w[d] + qjk_o[t1 * 64 + d] * fc_w[64 + d]
             + njk_o[t1 * 64 + d] * fc_w[128 + d] + njk_o[t0 * 64 + d] * fc_w[192 + d];
    #pragma unroll
    for (int off = 32; off > 0; off >>= 1) { r += __shfl_xor(r, off, 64); lf += __shfl_xor(lf, off, 64); }
    if (d == 0) out[b] = fmaxf(r + fc_b[0], lf + fc_b[0]);
}

// ---------------- host launcher ----------------

extern "C" void kernel_launch(void* const* d_in, const int* in_sizes, int n_in,
                              void* d_out, int out_size, void* d_ws, size_t ws_size,
                              hipStream_t stream) {
    const int* src   = (const int*)d_in[0];
    const int* dst   = (const int*)d_in[1];
    const int* etype = (const int*)d_in[2];
    const int* egid  = (const int*)d_in[3];
    const int* tgt   = (const int*)d_in[4];
    const float* query_emb = (const float*)d_in[6];
    const float* eqp_w = (const float*)d_in[7];
    const float* eqp_b = (const float*)d_in[8];
    const float* rel_w = (const float*)d_in[9];
    const float* gru_wx = (const float*)d_in[10];
    const float* gru_wh = (const float*)d_in[11];
    const float* gru_bx = (const float*)d_in[12];
    const float* gru_bh = (const float*)d_in[13];
    const float* pna_w = (const float*)d_in[14];
    const float* pna_b = (const float*)d_in[15];
    const float* lstm_wx = (const float*)d_in[16];
    const float* lstm_wh = (const float*)d_in[17];
    const float* lstm_b = (const float*)d_in[18];
    const float* ln_g = (const float*)d_in[19];
    const float* ln_b = (const float*)d_in[20];
    const float* ejk_w = (const float*)d_in[21];
    const float* ejk_b = (const float*)d_in[22];
    const float* njk_w = (const float*)d_in[23];
    const float* njk_b = (const float*)d_in[24];
    const float* qjk_w = (const float*)d_in[25];
    const float* qjk_b = (const float*)d_in[26];
    const float* fc_w = (const float*)d_in[27];
    const float* fc_b = (const float*)d_in[28];

    float* p = (float*)d_ws;
    float* equery = p;    p += (size_t)EN * 64;
    float* efeat = p;     p += (size_t)EN * 64;
    float* msg = p;       p += (size_t)EN * 64;
    float* nfeat = p;     p += (size_t)NN * 64;
    float* nfeat_new = p; p += (size_t)NN * 64;
    float* tgt_q = p;     p += 64 * 64;
    float* eq_g = p;      p += 32 * 64;
    float* jk_e = p;      p += 3 * 64 * 64;
    float* jk_q = p;      p += 3 * 64 * 64;
    float* jk_n = p;      p += 3 * 64 * 64;
    float* ejk_o = p;     p += 64 * 64;
    float* qjk_o = p;     p += 64 * 64;
    float* njk_o = p;     p += 64 * 64;
    float* avg_sum = p;   p += 64;
    unsigned short* wpg = (unsigned short*)p;   // 3*32768 bf16
    unsigned short* wpl = wpg + 3 * 32768;      // 3*32768 bf16
    unsigned short* wpp = wpl + 3 * 32768;      // 3*49152 bf16
    int* ip = (int*)(wpp + 3 * 49152);
    int* row_ptr = ip; ip += NN + 1;
    int* fillp = ip;   ip += NN;
    int* cnt = ip;     ip += NN;
    int* outcnt = ip;  ip += NN;
    int* eid = ip;     ip += EN;
    if ((size_t)((char*)ip - (char*)d_ws) > ws_size) return;

    k_init<<<4096, 256, 0, stream>>>(efeat, nfeat, cnt, outcnt, avg_sum);
    k_count<<<1024, 256, 0, stream>>>(src, dst, cnt, outcnt);
    k_scan<<<1, 1024, 0, stream>>>(cnt, row_ptr, fillp);
    k_fill<<<1024, 256, 0, stream>>>(dst, fillp, eid);
    k_avg<<<(NN + 255) / 256, 256, 0, stream>>>(outcnt, avg_sum);
    k_tgt<<<64, 64, 0, stream>>>(tgt, etype, query_emb, tgt_q, efeat);
    k_eqg<<<32, 64, 0, stream>>>(tgt_q, eqp_w, eqp_b, eq_g);
    k_equery<<<8192, 256, 0, stream>>>(egid, eq_g, equery);
    k_pack_gru<<<dim3(16, 3), 256, 0, stream>>>(gru_wx, gru_wh, wpg);
    k_pack_lstm<<<dim3(16, 3), 256, 0, stream>>>(lstm_wx, lstm_wh, wpl);
    k_pack_pna<<<dim3(24, 3), 256, 0, stream>>>(pna_w, wpp);

    for (int l = 0; l < 3; l++) {
        k_gru<<<1000, 512, 0, stream>>>(src, etype, nfeat, equery, efeat,
            rel_w + (size_t)l * NR * 64, wpg + (size_t)l * 32768,
            gru_bx + (size_t)l * 192, gru_bh + (size_t)l * 192, msg);
        k_node<<<NN / 16, 256, 0, stream>>>(row_ptr, eid, msg, avg_sum,
            wpp + (size_t)l * 49152, pna_b + (size_t)l * 64,
            ln_g + (size_t)l * 64, ln_b + (size_t)l * 64, nfeat, nfeat_new);
        k_lstm<<<1000, 512, 0, stream>>>(dst, nfeat_new, wpl + (size_t)l * 32768,
            lstm_b + (size_t)l * 256,
            ln_g + (size_t)l * 64, ln_b + (size_t)l * 64, efeat, equery);
        k_snap<<<64, 64, 0, stream>>>(tgt, src, efeat, equery, nfeat,
            jk_e + l * 4096, jk_q + l * 4096, jk_n + l * 4096);
    }

    k_jk<<<64, 64, 0, stream>>>(jk_e, jk_q, jk_n, ejk_w, ejk_b, qjk_w, qjk_b, njk_w, njk_b,
                                ejk_o, qjk_o, njk_o);
    k_final<<<32, 64, 0, stream>>>(ejk_o, qjk_o, njk_o, fc_w, fc_b, (float*)d_out);
}